// Round 1
// baseline (3766.505 us; speedup 1.0000x reference)
//
#include <hip/hip_runtime.h>
#include <hip/hip_bf16.h>

#define BB   128
#define CIN  9
#define TT   2048
#define RR   512
#define NN   (BB*RR)     // 65536
#define HID  128
#define NOUT 12

// ---------------- degree / norm ----------------
__global__ __launch_bounds__(256) void k_deg(const int* __restrict__ ei, int E,
                                             float* __restrict__ deg) {
    int i = blockIdx.x * 256 + threadIdx.x;
    if (i < E) unsafeAtomicAdd(&deg[ei[E + i]], 1.0f);
}

__global__ __launch_bounds__(256) void k_disv(float* __restrict__ deg) {
    int n = blockIdx.x * 256 + threadIdx.x;
    deg[n] = rsqrtf(deg[n] + 1.0f);   // +1 self-loop; deg>=1 always
}

// ---------------- conv1 (9->16,k5,pad2) + relu + maxpool2 ----------------
__global__ __launch_bounds__(256) void k_conv1(const float* __restrict__ x,
        const float* __restrict__ w, const float* __restrict__ bias,
        float* __restrict__ out1) {
    __shared__ float sx[CIN][260];
    __shared__ float sw[16 * CIN * 5];
    __shared__ float sb[16];
    int b  = blockIdx.x >> 3;
    int t0 = (blockIdx.x & 7) * 128;        // t_out base (out of 1024)
    int tid = threadIdx.x;
    for (int idx = tid; idx < CIN * 260; idx += 256) {
        int c = idx / 260, j = idx - c * 260;
        int g = 2 * t0 - 2 + j;
        float v = 0.f;
        if (g >= 0 && g < TT) v = x[(b * CIN + c) * TT + g];
        sx[c][j] = v;
    }
    for (int idx = tid; idx < 16 * CIN * 5; idx += 256) sw[idx] = w[idx];
    if (tid < 16) sb[tid] = bias[tid];
    __syncthreads();

    int rl   = tid & 127;   // local t_out
    int half = tid >> 7;    // 0/1 -> 8 channels each
    float acc0[8], acc1[8];
#pragma unroll
    for (int o = 0; o < 8; ++o) { float bv = sb[half * 8 + o]; acc0[o] = bv; acc1[o] = bv; }
#pragma unroll
    for (int c = 0; c < CIN; ++c) {
        float xv[6];
#pragma unroll
        for (int k = 0; k < 6; ++k) xv[k] = sx[c][2 * rl + k];
#pragma unroll
        for (int o = 0; o < 8; ++o) {
            int oo = half * 8 + o;
#pragma unroll
            for (int k = 0; k < 5; ++k) {
                float wv = sw[(oo * CIN + c) * 5 + k];
                acc0[o] += xv[k]     * wv;
                acc1[o] += xv[k + 1] * wv;
            }
        }
    }
#pragma unroll
    for (int o = 0; o < 8; ++o) {
        int oo = half * 8 + o;
        out1[(b * 16 + oo) * 1024 + t0 + rl] = fmaxf(fmaxf(acc0[o], acc1[o]), 0.f);
    }
}

// ---------------- conv2 (16->32,k5,pad2) + relu + maxpool2 -> nodes[N,32] ----
__global__ __launch_bounds__(256) void k_conv2(const float* __restrict__ in,
        const float* __restrict__ w, const float* __restrict__ bias,
        float* __restrict__ nodes) {
    __shared__ float sx[16][260];
    __shared__ float sw[32 * 16 * 5];
    __shared__ float sb[32];
    int b  = blockIdx.x >> 2;
    int r0 = (blockIdx.x & 3) * 128;        // r base (out of 512)
    int tid = threadIdx.x;
    for (int idx = tid; idx < 16 * 260; idx += 256) {
        int c = idx / 260, j = idx - c * 260;
        int g = 2 * r0 - 2 + j;
        float v = 0.f;
        if (g >= 0 && g < 1024) v = in[(b * 16 + c) * 1024 + g];
        sx[c][j] = v;
    }
    for (int idx = tid; idx < 32 * 16 * 5; idx += 256) sw[idx] = w[idx];
    if (tid < 32) sb[tid] = bias[tid];
    __syncthreads();

    int rl   = tid & 127;
    int half = tid >> 7;    // 0/1 -> 16 channels each
    float acc0[16], acc1[16];
#pragma unroll
    for (int o = 0; o < 16; ++o) { float bv = sb[half * 16 + o]; acc0[o] = bv; acc1[o] = bv; }
#pragma unroll
    for (int c = 0; c < 16; ++c) {
        float xv[6];
#pragma unroll
        for (int k = 0; k < 6; ++k) xv[k] = sx[c][2 * rl + k];
#pragma unroll
        for (int o = 0; o < 16; ++o) {
            int oo = half * 16 + o;
#pragma unroll
            for (int k = 0; k < 5; ++k) {
                float wv = sw[(oo * 16 + c) * 5 + k];
                acc0[o] += xv[k]     * wv;
                acc1[o] += xv[k + 1] * wv;
            }
        }
    }
    int n = b * RR + r0 + rl;
#pragma unroll
    for (int o = 0; o < 16; ++o) {
        int oo = half * 16 + o;
        nodes[n * 32 + oo] = fmaxf(fmaxf(acc0[o], acc1[o]), 0.f);
    }
}

// ---------------- lin1: h[N,128] = nodes[N,32] @ W[32,128] ----------------
__global__ __launch_bounds__(256) void k_lin1(const float* __restrict__ nodes,
        const float* __restrict__ w, float* __restrict__ h) {
    __shared__ float srow[32 * 32];     // 32 nodes x 32 feats
    __shared__ float sw[32 * 128];
    int tid = threadIdx.x;
    int nbase = blockIdx.x * 32;
    {   // 1024 floats = 256 float4
        const float4* src = (const float4*)(nodes + (size_t)nbase * 32);
        ((float4*)srow)[tid] = src[tid];
    }
    {   // 4096 floats = 1024 float4
        const float4* src = (const float4*)w;
        float4* dst = (float4*)sw;
#pragma unroll
        for (int i = 0; i < 4; ++i) dst[tid + i * 256] = src[tid + i * 256];
    }
    __syncthreads();
    int fq = tid & 31;   // f = fq*4
    int ng = tid >> 5;   // node group: nodes ng*4 .. ng*4+3
    float acc[4][4];
#pragma unroll
    for (int j = 0; j < 4; ++j)
#pragma unroll
        for (int q = 0; q < 4; ++q) acc[j][q] = 0.f;
#pragma unroll
    for (int c = 0; c < 32; ++c) {
        float4 wv = *(const float4*)&sw[c * 128 + fq * 4];
#pragma unroll
        for (int j = 0; j < 4; ++j) {
            float xc = srow[(ng * 4 + j) * 32 + c];
            acc[j][0] += xc * wv.x; acc[j][1] += xc * wv.y;
            acc[j][2] += xc * wv.z; acc[j][3] += xc * wv.w;
        }
    }
#pragma unroll
    for (int j = 0; j < 4; ++j) {
        float4 r = make_float4(acc[j][0], acc[j][1], acc[j][2], acc[j][3]);
        *(float4*)&h[(size_t)(nbase + ng * 4 + j) * 128 + fq * 4] = r;
    }
}

// ---------------- lin2: h[N,128] = g[N,128] @ W[128,128] ----------------
__global__ __launch_bounds__(256) void k_lin2(const float* __restrict__ g,
        const float* __restrict__ w, float* __restrict__ h) {
    __shared__ float srow[32 * 128];    // 32 nodes x 128 feats (16 KB)
    __shared__ float swc[64 * 128];     // W chunk (32 KB)
    int tid = threadIdx.x;
    int nbase = blockIdx.x * 32;
    {   // 4096 floats = 1024 float4
        const float4* src = (const float4*)(g + (size_t)nbase * 128);
        float4* dst = (float4*)srow;
#pragma unroll
        for (int i = 0; i < 4; ++i) dst[tid + i * 256] = src[tid + i * 256];
    }
    int fq = tid & 31;
    int ng = tid >> 5;
    float acc[4][4];
#pragma unroll
    for (int j = 0; j < 4; ++j)
#pragma unroll
        for (int q = 0; q < 4; ++q) acc[j][q] = 0.f;

    for (int ch = 0; ch < 2; ++ch) {
        if (ch) __syncthreads();
        {   // 8192 floats = 2048 float4
            const float4* src = (const float4*)(w + ch * 64 * 128);
            float4* dst = (float4*)swc;
#pragma unroll
            for (int i = 0; i < 8; ++i) dst[tid + i * 256] = src[tid + i * 256];
        }
        __syncthreads();
        int c0 = ch * 64;
#pragma unroll
        for (int c = 0; c < 64; ++c) {
            float4 wv = *(const float4*)&swc[c * 128 + fq * 4];
#pragma unroll
            for (int j = 0; j < 4; ++j) {
                float xc = srow[(ng * 4 + j) * 128 + c0 + c];
                acc[j][0] += xc * wv.x; acc[j][1] += xc * wv.y;
                acc[j][2] += xc * wv.z; acc[j][3] += xc * wv.w;
            }
        }
    }
#pragma unroll
    for (int j = 0; j < 4; ++j) {
        float4 r = make_float4(acc[j][0], acc[j][1], acc[j][2], acc[j][3]);
        *(float4*)&h[(size_t)(nbase + ng * 4 + j) * 128 + fq * 4] = r;
    }
}

// ---------------- edge aggregation: out[col] += dis[row]*dis[col]*h[row] ----
__global__ __launch_bounds__(256) void k_agg(const int* __restrict__ ei, int E,
        const float* __restrict__ dis, const float* __restrict__ h,
        float* __restrict__ out) {
    int tid = threadIdx.x;
    int e = blockIdx.x * 8 + (tid >> 5);
    if (e >= E) return;
    int lane = tid & 31;
    int row = ei[e];
    int col = ei[E + e];
    float norm = dis[row] * dis[col];
    float4 v = *(const float4*)&h[(size_t)row * 128 + lane * 4];
    float* dst = &out[(size_t)col * 128 + lane * 4];
    unsafeAtomicAdd(dst + 0, norm * v.x);
    unsafeAtomicAdd(dst + 1, norm * v.y);
    unsafeAtomicAdd(dst + 2, norm * v.z);
    unsafeAtomicAdd(dst + 3, norm * v.w);
}

// ---------------- finalize: g = relu(agg + dis^2 * h + bias) ----------------
__global__ __launch_bounds__(256) void k_fin(float* __restrict__ agg,
        const float* __restrict__ h, const float* __restrict__ dis,
        const float* __restrict__ bias) {
    size_t idx = (size_t)blockIdx.x * 256 + threadIdx.x;
    int n = (int)(idx >> 7), f = (int)(idx & 127);
    float d = dis[n];
    float v = agg[idx] + d * d * h[idx] + bias[f];
    agg[idx] = fmaxf(v, 0.f);
}

// ---------------- mean over R + fc ----------------
__global__ __launch_bounds__(128) void k_meanfc(const float* __restrict__ g,
        const float* __restrict__ fw, const float* __restrict__ fb,
        float* __restrict__ out) {
    __shared__ float sm[HID];
    int b = blockIdx.x, f = threadIdx.x;
    float acc = 0.f;
    const float* p = g + (size_t)b * RR * HID + f;
    for (int r = 0; r < RR; ++r) acc += p[(size_t)r * HID];
    sm[f] = acc * (1.0f / RR);
    __syncthreads();
    if (f < NOUT) {
        float s = fb[f];
#pragma unroll
        for (int c = 0; c < HID; ++c) s += sm[c] * fw[c * NOUT + f];
        out[b * NOUT + f] = s;
    }
}

extern "C" void kernel_launch(void* const* d_in, const int* in_sizes, int n_in,
                              void* d_out, int out_size, void* d_ws, size_t ws_size,
                              hipStream_t stream) {
    const float* x   = (const float*)d_in[0];
    const int*   ei  = (const int*)d_in[1];
    const float* c1w = (const float*)d_in[2];
    const float* c1b = (const float*)d_in[3];
    const float* c2w = (const float*)d_in[4];
    const float* c2b = (const float*)d_in[5];
    const float* g1w = (const float*)d_in[6];
    const float* g1b = (const float*)d_in[7];
    const float* g2w = (const float*)d_in[8];
    const float* g2b = (const float*)d_in[9];
    const float* fw  = (const float*)d_in[10];
    const float* fb  = (const float*)d_in[11];
    float* out = (float*)d_out;
    int E = in_sizes[1] / 2;   // 1048576

    char* ws = (char*)d_ws;
    float* out1  = (float*)(ws);                              // 8 MB  [B,16,1024]
    float* nodes = (float*)(ws + (size_t)(8u << 20));         // 8 MB  [N,32]
    float* dis   = (float*)(ws + (size_t)(16u << 20));        // 256 KB [N]
    float* bufA  = (float*)(ws + (size_t)(16u << 20) + (1u << 18)); // 32 MB [N,128]
    float* bufB  = (float*)(ws + (size_t)(48u << 20) + (1u << 18)); // 32 MB [N,128]

    // degrees -> dis = rsqrt(deg+1)
    hipMemsetAsync(dis, 0, (size_t)NN * 4, stream);
    k_deg<<<(E + 255) / 256, 256, 0, stream>>>(ei, E, dis);
    k_disv<<<NN / 256, 256, 0, stream>>>(dis);

    // temporal convs
    k_conv1<<<BB * 8, 256, 0, stream>>>(x, c1w, c1b, out1);
    k_conv2<<<BB * 4, 256, 0, stream>>>(out1, c2w, c2b, nodes);

    // GCN layer 1
    k_lin1<<<NN / 32, 256, 0, stream>>>(nodes, g1w, bufA);
    hipMemsetAsync(bufB, 0, (size_t)NN * HID * 4, stream);
    k_agg<<<(E + 7) / 8, 256, 0, stream>>>(ei, E, dis, bufA, bufB);
    k_fin<<<NN * HID / 256, 256, 0, stream>>>(bufB, bufA, dis, g1b);

    // GCN layer 2
    k_lin2<<<NN / 32, 256, 0, stream>>>(bufB, g2w, bufA);
    hipMemsetAsync(bufB, 0, (size_t)NN * HID * 4, stream);
    k_agg<<<(E + 7) / 8, 256, 0, stream>>>(ei, E, dis, bufA, bufB);
    k_fin<<<NN * HID / 256, 256, 0, stream>>>(bufB, bufA, dis, g2b);

    // mean + fc
    k_meanfc<<<BB, 128, 0, stream>>>(bufB, fw, fb, out);
}

// Round 2
// 361.077 us; speedup vs baseline: 10.4313x; 10.4313x over previous
//
#include <hip/hip_runtime.h>
#include <hip/hip_bf16.h>

#define BB   128
#define CIN  9
#define TT   2048
#define RR   512
#define NN   (BB*RR)     // 65536
#define HID  128
#define NOUT 12

// ---------------- degree count (int) ----------------
__global__ __launch_bounds__(256) void k_deg(const int* __restrict__ ei, int E,
                                             int* __restrict__ cnt) {
    int i = blockIdx.x * 256 + threadIdx.x;
    if (i < E) atomicAdd(&cnt[ei[E + i]], 1);
}

// dis = rsqrt(deg+1)  (+1 = self loop, so deg>=1 always)
__global__ __launch_bounds__(256) void k_disv(const int* __restrict__ cnt,
                                              float* __restrict__ dis) {
    int n = blockIdx.x * 256 + threadIdx.x;
    dis[n] = rsqrtf((float)cnt[n] + 1.0f);
}

// ---------------- exclusive scan over 65536 counts -> rptr ----------------
__global__ __launch_bounds__(1024) void k_scan(const int* __restrict__ cnt,
                                               int* __restrict__ rptr) {
    __shared__ int sp[1024];
    int tid = threadIdx.x;
    int base = tid * 64;
    int s = 0;
    for (int j = 0; j < 64; ++j) s += cnt[base + j];
    sp[tid] = s;
    __syncthreads();
    for (int off = 1; off < 1024; off <<= 1) {
        int v = sp[tid];
        int add = (tid >= off) ? sp[tid - off] : 0;
        __syncthreads();
        sp[tid] = v + add;
        __syncthreads();
    }
    int run = sp[tid] - s;   // exclusive prefix for this chunk
    for (int j = 0; j < 64; ++j) { rptr[base + j] = run; run += cnt[base + j]; }
    if (tid == 1023) rptr[NN] = run;
}

// ---------------- scatter edges into CSR ----------------
__global__ __launch_bounds__(256) void k_scatter(const int* __restrict__ ei, int E,
        const int* __restrict__ rptr, int* __restrict__ cursor,
        int* __restrict__ adj) {
    int i = blockIdx.x * 256 + threadIdx.x;
    if (i >= E) return;
    int row = ei[i];
    int col = ei[E + i];
    int pos = atomicAdd(&cursor[col], 1);
    adj[rptr[col] + pos] = row;
}

// ---------------- conv1 (9->16,k5,pad2) + relu + maxpool2 ----------------
__global__ __launch_bounds__(256) void k_conv1(const float* __restrict__ x,
        const float* __restrict__ w, const float* __restrict__ bias,
        float* __restrict__ out1) {
    __shared__ float sx[CIN][260];
    __shared__ float sw[16 * CIN * 5];
    __shared__ float sb[16];
    int b  = blockIdx.x >> 3;
    int t0 = (blockIdx.x & 7) * 128;        // t_out base (out of 1024)
    int tid = threadIdx.x;
    for (int idx = tid; idx < CIN * 260; idx += 256) {
        int c = idx / 260, j = idx - c * 260;
        int g = 2 * t0 - 2 + j;
        float v = 0.f;
        if (g >= 0 && g < TT) v = x[(b * CIN + c) * TT + g];
        sx[c][j] = v;
    }
    for (int idx = tid; idx < 16 * CIN * 5; idx += 256) sw[idx] = w[idx];
    if (tid < 16) sb[tid] = bias[tid];
    __syncthreads();

    int rl   = tid & 127;   // local t_out
    int half = tid >> 7;    // 0/1 -> 8 channels each
    float acc0[8], acc1[8];
#pragma unroll
    for (int o = 0; o < 8; ++o) { float bv = sb[half * 8 + o]; acc0[o] = bv; acc1[o] = bv; }
#pragma unroll
    for (int c = 0; c < CIN; ++c) {
        float xv[6];
#pragma unroll
        for (int k = 0; k < 6; ++k) xv[k] = sx[c][2 * rl + k];
#pragma unroll
        for (int o = 0; o < 8; ++o) {
            int oo = half * 8 + o;
#pragma unroll
            for (int k = 0; k < 5; ++k) {
                float wv = sw[(oo * CIN + c) * 5 + k];
                acc0[o] += xv[k]     * wv;
                acc1[o] += xv[k + 1] * wv;
            }
        }
    }
#pragma unroll
    for (int o = 0; o < 8; ++o) {
        int oo = half * 8 + o;
        out1[(b * 16 + oo) * 1024 + t0 + rl] = fmaxf(fmaxf(acc0[o], acc1[o]), 0.f);
    }
}

// ---------------- conv2 (16->32,k5,pad2) + relu + maxpool2 -> nodes[N,32] ----
__global__ __launch_bounds__(256) void k_conv2(const float* __restrict__ in,
        const float* __restrict__ w, const float* __restrict__ bias,
        float* __restrict__ nodes) {
    __shared__ float sx[16][260];
    __shared__ float sw[32 * 16 * 5];
    __shared__ float sb[32];
    int b  = blockIdx.x >> 2;
    int r0 = (blockIdx.x & 3) * 128;        // r base (out of 512)
    int tid = threadIdx.x;
    for (int idx = tid; idx < 16 * 260; idx += 256) {
        int c = idx / 260, j = idx - c * 260;
        int g = 2 * r0 - 2 + j;
        float v = 0.f;
        if (g >= 0 && g < 1024) v = in[(b * 16 + c) * 1024 + g];
        sx[c][j] = v;
    }
    for (int idx = tid; idx < 32 * 16 * 5; idx += 256) sw[idx] = w[idx];
    if (tid < 32) sb[tid] = bias[tid];
    __syncthreads();

    int rl   = tid & 127;
    int half = tid >> 7;    // 0/1 -> 16 channels each
    float acc0[16], acc1[16];
#pragma unroll
    for (int o = 0; o < 16; ++o) { float bv = sb[half * 16 + o]; acc0[o] = bv; acc1[o] = bv; }
#pragma unroll
    for (int c = 0; c < 16; ++c) {
        float xv[6];
#pragma unroll
        for (int k = 0; k < 6; ++k) xv[k] = sx[c][2 * rl + k];
#pragma unroll
        for (int o = 0; o < 16; ++o) {
            int oo = half * 16 + o;
#pragma unroll
            for (int k = 0; k < 5; ++k) {
                float wv = sw[(oo * 16 + c) * 5 + k];
                acc0[o] += xv[k]     * wv;
                acc1[o] += xv[k + 1] * wv;
            }
        }
    }
    int n = b * RR + r0 + rl;
#pragma unroll
    for (int o = 0; o < 16; ++o) {
        int oo = half * 16 + o;
        nodes[n * 32 + oo] = fmaxf(fmaxf(acc0[o], acc1[o]), 0.f);
    }
}

// ---------------- lin1: h[N,128] = nodes[N,32] @ W[32,128] ----------------
__global__ __launch_bounds__(256) void k_lin1(const float* __restrict__ nodes,
        const float* __restrict__ w, float* __restrict__ h) {
    __shared__ float srow[32 * 32];     // 32 nodes x 32 feats
    __shared__ float sw[32 * 128];
    int tid = threadIdx.x;
    int nbase = blockIdx.x * 32;
    {   // 1024 floats = 256 float4
        const float4* src = (const float4*)(nodes + (size_t)nbase * 32);
        ((float4*)srow)[tid] = src[tid];
    }
    {   // 4096 floats = 1024 float4
        const float4* src = (const float4*)w;
        float4* dst = (float4*)sw;
#pragma unroll
        for (int i = 0; i < 4; ++i) dst[tid + i * 256] = src[tid + i * 256];
    }
    __syncthreads();
    int fq = tid & 31;   // f = fq*4
    int ng = tid >> 5;   // node group: nodes ng*4 .. ng*4+3
    float acc[4][4];
#pragma unroll
    for (int j = 0; j < 4; ++j)
#pragma unroll
        for (int q = 0; q < 4; ++q) acc[j][q] = 0.f;
#pragma unroll
    for (int c = 0; c < 32; ++c) {
        float4 wv = *(const float4*)&sw[c * 128 + fq * 4];
#pragma unroll
        for (int j = 0; j < 4; ++j) {
            float xc = srow[(ng * 4 + j) * 32 + c];
            acc[j][0] += xc * wv.x; acc[j][1] += xc * wv.y;
            acc[j][2] += xc * wv.z; acc[j][3] += xc * wv.w;
        }
    }
#pragma unroll
    for (int j = 0; j < 4; ++j) {
        float4 r = make_float4(acc[j][0], acc[j][1], acc[j][2], acc[j][3]);
        *(float4*)&h[(size_t)(nbase + ng * 4 + j) * 128 + fq * 4] = r;
    }
}

// ---------------- lin2: h[N,128] = g[N,128] @ W[128,128] ----------------
__global__ __launch_bounds__(256) void k_lin2(const float* __restrict__ g,
        const float* __restrict__ w, float* __restrict__ h) {
    __shared__ float srow[32 * 128];    // 32 nodes x 128 feats (16 KB)
    __shared__ float swc[64 * 128];     // W chunk (32 KB)
    int tid = threadIdx.x;
    int nbase = blockIdx.x * 32;
    {   // 4096 floats = 1024 float4
        const float4* src = (const float4*)(g + (size_t)nbase * 128);
        float4* dst = (float4*)srow;
#pragma unroll
        for (int i = 0; i < 4; ++i) dst[tid + i * 256] = src[tid + i * 256];
    }
    int fq = tid & 31;
    int ng = tid >> 5;
    float acc[4][4];
#pragma unroll
    for (int j = 0; j < 4; ++j)
#pragma unroll
        for (int q = 0; q < 4; ++q) acc[j][q] = 0.f;

    for (int ch = 0; ch < 2; ++ch) {
        if (ch) __syncthreads();
        {   // 8192 floats = 2048 float4
            const float4* src = (const float4*)(w + ch * 64 * 128);
            float4* dst = (float4*)swc;
#pragma unroll
            for (int i = 0; i < 8; ++i) dst[tid + i * 256] = src[tid + i * 256];
        }
        __syncthreads();
        int c0 = ch * 64;
#pragma unroll
        for (int c = 0; c < 64; ++c) {
            float4 wv = *(const float4*)&swc[c * 128 + fq * 4];
#pragma unroll
            for (int j = 0; j < 4; ++j) {
                float xc = srow[(ng * 4 + j) * 128 + c0 + c];
                acc[j][0] += xc * wv.x; acc[j][1] += xc * wv.y;
                acc[j][2] += xc * wv.z; acc[j][3] += xc * wv.w;
            }
        }
    }
#pragma unroll
    for (int j = 0; j < 4; ++j) {
        float4 r = make_float4(acc[j][0], acc[j][1], acc[j][2], acc[j][3]);
        *(float4*)&h[(size_t)(nbase + ng * 4 + j) * 128 + fq * 4] = r;
    }
}

// ---- gather aggregation + self-loop + bias + relu (replaces k_agg/k_fin) ----
// out[n] = relu( sum_{src in N(n)} dis[src]*dis[n]*h[src] + dis[n]^2*h[n] + b )
__global__ __launch_bounds__(256) void k_gather(const int* __restrict__ rptr,
        const int* __restrict__ adj, const float* __restrict__ dis,
        const float* __restrict__ h, const float* __restrict__ bias,
        float* __restrict__ out) {
    int tid  = threadIdx.x;
    int node = blockIdx.x * 8 + (tid >> 5);
    int lane = tid & 31;
    int s = rptr[node], e = rptr[node + 1];
    float dn = dis[node];
    float4 acc = make_float4(0.f, 0.f, 0.f, 0.f);
    for (int base = s; base < e; base += 32) {
        int j = base + lane;
        int src = 0; float nd = 0.f;
        if (j < e) { src = adj[j]; nd = dis[src]; }
        int cnt = min(32, e - base);
        for (int k = 0; k < cnt; ++k) {
            int   sk = __shfl(src, k, 32);
            float nk = __shfl(nd, k, 32);
            float4 v = *(const float4*)&h[(size_t)sk * 128 + lane * 4];
            float wgt = dn * nk;
            acc.x += wgt * v.x; acc.y += wgt * v.y;
            acc.z += wgt * v.z; acc.w += wgt * v.w;
        }
    }
    // self loop
    float4 v = *(const float4*)&h[(size_t)node * 128 + lane * 4];
    float wgt = dn * dn;
    float4 bv = *(const float4*)&bias[lane * 4];
    acc.x = fmaxf(acc.x + wgt * v.x + bv.x, 0.f);
    acc.y = fmaxf(acc.y + wgt * v.y + bv.y, 0.f);
    acc.z = fmaxf(acc.z + wgt * v.z + bv.z, 0.f);
    acc.w = fmaxf(acc.w + wgt * v.w + bv.w, 0.f);
    *(float4*)&out[(size_t)node * 128 + lane * 4] = acc;
}

// ---------------- mean over R + fc ----------------
__global__ __launch_bounds__(128) void k_meanfc(const float* __restrict__ g,
        const float* __restrict__ fw, const float* __restrict__ fb,
        float* __restrict__ out) {
    __shared__ float sm[HID];
    int b = blockIdx.x, f = threadIdx.x;
    float acc = 0.f;
    const float* p = g + (size_t)b * RR * HID + f;
    for (int r = 0; r < RR; ++r) acc += p[(size_t)r * HID];
    sm[f] = acc * (1.0f / RR);
    __syncthreads();
    if (f < NOUT) {
        float s = fb[f];
#pragma unroll
        for (int c = 0; c < HID; ++c) s += sm[c] * fw[c * NOUT + f];
        out[b * NOUT + f] = s;
    }
}

extern "C" void kernel_launch(void* const* d_in, const int* in_sizes, int n_in,
                              void* d_out, int out_size, void* d_ws, size_t ws_size,
                              hipStream_t stream) {
    const float* x   = (const float*)d_in[0];
    const int*   ei  = (const int*)d_in[1];
    const float* c1w = (const float*)d_in[2];
    const float* c1b = (const float*)d_in[3];
    const float* c2w = (const float*)d_in[4];
    const float* c2b = (const float*)d_in[5];
    const float* g1w = (const float*)d_in[6];
    const float* g1b = (const float*)d_in[7];
    const float* g2w = (const float*)d_in[8];
    const float* g2b = (const float*)d_in[9];
    const float* fw  = (const float*)d_in[10];
    const float* fb  = (const float*)d_in[11];
    float* out = (float*)d_out;
    int E = in_sizes[1] / 2;   // 1048576

    char* ws = (char*)d_ws;
    // region [0, 8MB): out1 during convs; graph CSR structures afterwards
    float* out1   = (float*)(ws);                                  // 8 MB [B,16,1024]
    int*   adj    = (int*)(ws);                                    // 4 MB [E]
    float* dis    = (float*)(ws + (4u << 20));                     // 256 KB [N]
    int*   cnt    = (int*)(ws + (4u << 20) + (1u << 18));          // 256 KB [N]
    int*   rptr   = (int*)(ws + (4u << 20) + 2 * (1u << 18));      // 256 KB+4 [N+1]
    int*   cursor = (int*)(ws + (4u << 20) + 3 * (1u << 18) + 4096); // 256 KB [N]
    float* nodes  = (float*)(ws + (8u << 20));                     // 8 MB [N,32]
    float* bufA   = (float*)(ws + (16u << 20));                    // 32 MB [N,128]
    float* bufB   = (float*)(ws + (48u << 20));                    // 32 MB [N,128]

    // temporal convs first (out1 region is reused by CSR afterwards)
    k_conv1<<<BB * 8, 256, 0, stream>>>(x, c1w, c1b, out1);
    k_conv2<<<BB * 4, 256, 0, stream>>>(out1, c2w, c2b, nodes);

    // CSR build + norms
    hipMemsetAsync(cnt, 0, (size_t)NN * 4, stream);
    hipMemsetAsync(cursor, 0, (size_t)NN * 4, stream);
    k_deg<<<(E + 255) / 256, 256, 0, stream>>>(ei, E, cnt);
    k_disv<<<NN / 256, 256, 0, stream>>>(cnt, dis);
    k_scan<<<1, 1024, 0, stream>>>(cnt, rptr);
    k_scatter<<<(E + 255) / 256, 256, 0, stream>>>(ei, E, rptr, cursor, adj);

    // GCN layer 1
    k_lin1<<<NN / 32, 256, 0, stream>>>(nodes, g1w, bufA);
    k_gather<<<NN / 8, 256, 0, stream>>>(rptr, adj, dis, bufA, g1b, bufB);

    // GCN layer 2
    k_lin2<<<NN / 32, 256, 0, stream>>>(bufB, g2w, bufA);
    k_gather<<<NN / 8, 256, 0, stream>>>(rptr, adj, dis, bufA, g2b, bufB);

    // mean + fc
    k_meanfc<<<BB, 128, 0, stream>>>(bufB, fw, fb, out);
}

// Round 3
// 290.301 us; speedup vs baseline: 12.9745x; 1.2438x over previous
//
#include <hip/hip_runtime.h>
#include <hip/hip_bf16.h>

#define BB   128
#define CIN  9
#define TT   2048
#define RR   512
#define NN   (BB*RR)     // 65536
#define HID  128
#define NOUT 12

// ---------------- degree count (int) ----------------
__global__ __launch_bounds__(256) void k_deg(const int* __restrict__ ei, int E,
                                             int* __restrict__ cnt) {
    int i = blockIdx.x * 256 + threadIdx.x;
    if (i < E) atomicAdd(&cnt[ei[E + i]], 1);
}

// dis = rsqrt(deg+1)  (+1 = self loop, so deg>=1 always)
__global__ __launch_bounds__(256) void k_disv(const int* __restrict__ cnt,
                                              float* __restrict__ dis) {
    int n = blockIdx.x * 256 + threadIdx.x;
    dis[n] = rsqrtf((float)cnt[n] + 1.0f);
}

// ---------------- exclusive scan over 65536 counts -> rptr ----------------
__global__ __launch_bounds__(1024) void k_scan(const int* __restrict__ cnt,
                                               int* __restrict__ rptr) {
    __shared__ int sp[1024];
    int tid = threadIdx.x;
    int base = tid * 64;
    int s = 0;
    for (int j = 0; j < 64; ++j) s += cnt[base + j];
    sp[tid] = s;
    __syncthreads();
    for (int off = 1; off < 1024; off <<= 1) {
        int v = sp[tid];
        int add = (tid >= off) ? sp[tid - off] : 0;
        __syncthreads();
        sp[tid] = v + add;
        __syncthreads();
    }
    int run = sp[tid] - s;   // exclusive prefix for this chunk
    for (int j = 0; j < 64; ++j) { rptr[base + j] = run; run += cnt[base + j]; }
    if (tid == 1023) rptr[NN] = run;
}

// ---------------- scatter edges into CSR ----------------
__global__ __launch_bounds__(256) void k_scatter(const int* __restrict__ ei, int E,
        const int* __restrict__ rptr, int* __restrict__ cursor,
        int* __restrict__ adj) {
    int i = blockIdx.x * 256 + threadIdx.x;
    if (i >= E) return;
    int row = ei[i];
    int col = ei[E + i];
    int pos = atomicAdd(&cursor[col], 1);
    adj[rptr[col] + pos] = row;
}

// ---------------- conv1 (9->16,k5,pad2) + relu + maxpool2 ----------------
__global__ __launch_bounds__(256) void k_conv1(const float* __restrict__ x,
        const float* __restrict__ w, const float* __restrict__ bias,
        float* __restrict__ out1) {
    __shared__ float sx[CIN][260];
    __shared__ float sw[16 * CIN * 5];
    __shared__ float sb[16];
    int b  = blockIdx.x >> 3;
    int t0 = (blockIdx.x & 7) * 128;
    int tid = threadIdx.x;
    for (int idx = tid; idx < CIN * 260; idx += 256) {
        int c = idx / 260, j = idx - c * 260;
        int g = 2 * t0 - 2 + j;
        float v = 0.f;
        if (g >= 0 && g < TT) v = x[(b * CIN + c) * TT + g];
        sx[c][j] = v;
    }
    for (int idx = tid; idx < 16 * CIN * 5; idx += 256) sw[idx] = w[idx];
    if (tid < 16) sb[tid] = bias[tid];
    __syncthreads();

    int rl   = tid & 127;
    int half = tid >> 7;
    float acc0[8], acc1[8];
#pragma unroll
    for (int o = 0; o < 8; ++o) { float bv = sb[half * 8 + o]; acc0[o] = bv; acc1[o] = bv; }
#pragma unroll
    for (int c = 0; c < CIN; ++c) {
        float xv[6];
#pragma unroll
        for (int k = 0; k < 6; ++k) xv[k] = sx[c][2 * rl + k];
#pragma unroll
        for (int o = 0; o < 8; ++o) {
            int oo = half * 8 + o;
#pragma unroll
            for (int k = 0; k < 5; ++k) {
                float wv = sw[(oo * CIN + c) * 5 + k];
                acc0[o] += xv[k]     * wv;
                acc1[o] += xv[k + 1] * wv;
            }
        }
    }
#pragma unroll
    for (int o = 0; o < 8; ++o) {
        int oo = half * 8 + o;
        out1[(b * 16 + oo) * 1024 + t0 + rl] = fmaxf(fmaxf(acc0[o], acc1[o]), 0.f);
    }
}

// ---------------- conv2 (16->32,k5,pad2) + relu + maxpool2 -> nodes[N,32] ----
__global__ __launch_bounds__(256) void k_conv2(const float* __restrict__ in,
        const float* __restrict__ w, const float* __restrict__ bias,
        float* __restrict__ nodes) {
    __shared__ float sx[16][260];
    __shared__ float sw[32 * 16 * 5];
    __shared__ float sb[32];
    int b  = blockIdx.x >> 2;
    int r0 = (blockIdx.x & 3) * 128;
    int tid = threadIdx.x;
    for (int idx = tid; idx < 16 * 260; idx += 256) {
        int c = idx / 260, j = idx - c * 260;
        int g = 2 * r0 - 2 + j;
        float v = 0.f;
        if (g >= 0 && g < 1024) v = in[(b * 16 + c) * 1024 + g];
        sx[c][j] = v;
    }
    for (int idx = tid; idx < 32 * 16 * 5; idx += 256) sw[idx] = w[idx];
    if (tid < 32) sb[tid] = bias[tid];
    __syncthreads();

    int rl   = tid & 127;
    int half = tid >> 7;
    float acc0[16], acc1[16];
#pragma unroll
    for (int o = 0; o < 16; ++o) { float bv = sb[half * 16 + o]; acc0[o] = bv; acc1[o] = bv; }
#pragma unroll
    for (int c = 0; c < 16; ++c) {
        float xv[6];
#pragma unroll
        for (int k = 0; k < 6; ++k) xv[k] = sx[c][2 * rl + k];
#pragma unroll
        for (int o = 0; o < 16; ++o) {
            int oo = half * 16 + o;
#pragma unroll
            for (int k = 0; k < 5; ++k) {
                float wv = sw[(oo * 16 + c) * 5 + k];
                acc0[o] += xv[k]     * wv;
                acc1[o] += xv[k + 1] * wv;
            }
        }
    }
    int n = b * RR + r0 + rl;
#pragma unroll
    for (int o = 0; o < 16; ++o) {
        int oo = half * 16 + o;
        nodes[n * 32 + oo] = fmaxf(fmaxf(acc0[o], acc1[o]), 0.f);
    }
}

// ---- layer-1 pre-aggregation on 32-dim node features (agg commutes with W) --
__global__ __launch_bounds__(256) void k_gather32(const int* __restrict__ rptr,
        const int* __restrict__ adj, const float* __restrict__ dis,
        const float* __restrict__ h32, float* __restrict__ out) {
    int bid  = (blockIdx.x & 7) * 256 + (blockIdx.x >> 3);   // XCD swizzle, 2048 blocks
    int tid  = threadIdx.x;
    int node = bid * 32 + (tid >> 3);
    int lane = tid & 7;
    int s = rptr[node], e = rptr[node + 1];
    float dn = dis[node];
    float4 acc = make_float4(0.f, 0.f, 0.f, 0.f);
    for (int base = s; base < e; base += 8) {
        int j = base + lane;
        int src = 0; float nd = 0.f;
        if (j < e) { src = adj[j]; nd = dis[src]; }
        int cnt = min(8, e - base);
        int k = 0;
        for (; k + 4 <= cnt; k += 4) {
            int   s0 = __shfl(src, k, 8),     s1 = __shfl(src, k + 1, 8);
            int   s2 = __shfl(src, k + 2, 8), s3 = __shfl(src, k + 3, 8);
            float n0 = __shfl(nd, k, 8),      n1 = __shfl(nd, k + 1, 8);
            float n2 = __shfl(nd, k + 2, 8),  n3 = __shfl(nd, k + 3, 8);
            float4 v0 = *(const float4*)&h32[(size_t)s0 * 32 + lane * 4];
            float4 v1 = *(const float4*)&h32[(size_t)s1 * 32 + lane * 4];
            float4 v2 = *(const float4*)&h32[(size_t)s2 * 32 + lane * 4];
            float4 v3 = *(const float4*)&h32[(size_t)s3 * 32 + lane * 4];
            float w0 = dn * n0, w1 = dn * n1, w2 = dn * n2, w3 = dn * n3;
            acc.x += w0*v0.x + w1*v1.x + w2*v2.x + w3*v3.x;
            acc.y += w0*v0.y + w1*v1.y + w2*v2.y + w3*v3.y;
            acc.z += w0*v0.z + w1*v1.z + w2*v2.z + w3*v3.z;
            acc.w += w0*v0.w + w1*v1.w + w2*v2.w + w3*v3.w;
        }
        for (; k < cnt; ++k) {
            int   sk = __shfl(src, k, 8);
            float nk = __shfl(nd, k, 8);
            float4 v = *(const float4*)&h32[(size_t)sk * 32 + lane * 4];
            float wgt = dn * nk;
            acc.x += wgt * v.x; acc.y += wgt * v.y;
            acc.z += wgt * v.z; acc.w += wgt * v.w;
        }
    }
    float4 v = *(const float4*)&h32[(size_t)node * 32 + lane * 4];
    float wgt = dn * dn;
    acc.x += wgt * v.x; acc.y += wgt * v.y;
    acc.z += wgt * v.z; acc.w += wgt * v.w;
    *(float4*)&out[(size_t)node * 32 + lane * 4] = acc;
}

// ---------------- lin1: g[N,128] = relu(agg32[N,32] @ W[32,128] + b) --------
__global__ __launch_bounds__(256) void k_lin1(const float* __restrict__ agg32,
        const float* __restrict__ w, const float* __restrict__ bias,
        float* __restrict__ h) {
    __shared__ float srow[32 * 32];
    __shared__ float sw[32 * 128];
    int tid = threadIdx.x;
    int nbase = blockIdx.x * 32;
    {
        const float4* src = (const float4*)(agg32 + (size_t)nbase * 32);
        ((float4*)srow)[tid] = src[tid];
    }
    {
        const float4* src = (const float4*)w;
        float4* dst = (float4*)sw;
#pragma unroll
        for (int i = 0; i < 4; ++i) dst[tid + i * 256] = src[tid + i * 256];
    }
    __syncthreads();
    int fq = tid & 31;
    int ng = tid >> 5;
    float acc[4][4];
#pragma unroll
    for (int j = 0; j < 4; ++j)
#pragma unroll
        for (int q = 0; q < 4; ++q) acc[j][q] = 0.f;
#pragma unroll
    for (int c = 0; c < 32; ++c) {
        float4 wv = *(const float4*)&sw[c * 128 + fq * 4];
#pragma unroll
        for (int j = 0; j < 4; ++j) {
            float xc = srow[(ng * 4 + j) * 32 + c];
            acc[j][0] += xc * wv.x; acc[j][1] += xc * wv.y;
            acc[j][2] += xc * wv.z; acc[j][3] += xc * wv.w;
        }
    }
    float4 bv = *(const float4*)&bias[fq * 4];
#pragma unroll
    for (int j = 0; j < 4; ++j) {
        float4 r = make_float4(fmaxf(acc[j][0] + bv.x, 0.f),
                               fmaxf(acc[j][1] + bv.y, 0.f),
                               fmaxf(acc[j][2] + bv.z, 0.f),
                               fmaxf(acc[j][3] + bv.w, 0.f));
        *(float4*)&h[(size_t)(nbase + ng * 4 + j) * 128 + fq * 4] = r;
    }
}

// ---------------- lin2: h[N,128] = g[N,128] @ W[128,128] ----------------
__global__ __launch_bounds__(256) void k_lin2(const float* __restrict__ g,
        const float* __restrict__ w, float* __restrict__ h) {
    __shared__ float srow[32 * 128];
    __shared__ float swc[64 * 128];
    int tid = threadIdx.x;
    int nbase = blockIdx.x * 32;
    {
        const float4* src = (const float4*)(g + (size_t)nbase * 128);
        float4* dst = (float4*)srow;
#pragma unroll
        for (int i = 0; i < 4; ++i) dst[tid + i * 256] = src[tid + i * 256];
    }
    int fq = tid & 31;
    int ng = tid >> 5;
    float acc[4][4];
#pragma unroll
    for (int j = 0; j < 4; ++j)
#pragma unroll
        for (int q = 0; q < 4; ++q) acc[j][q] = 0.f;

    for (int ch = 0; ch < 2; ++ch) {
        if (ch) __syncthreads();
        {
            const float4* src = (const float4*)(w + ch * 64 * 128);
            float4* dst = (float4*)swc;
#pragma unroll
            for (int i = 0; i < 8; ++i) dst[tid + i * 256] = src[tid + i * 256];
        }
        __syncthreads();
        int c0 = ch * 64;
#pragma unroll
        for (int c = 0; c < 64; ++c) {
            float4 wv = *(const float4*)&swc[c * 128 + fq * 4];
#pragma unroll
            for (int j = 0; j < 4; ++j) {
                float xc = srow[(ng * 4 + j) * 128 + c0 + c];
                acc[j][0] += xc * wv.x; acc[j][1] += xc * wv.y;
                acc[j][2] += xc * wv.z; acc[j][3] += xc * wv.w;
            }
        }
    }
#pragma unroll
    for (int j = 0; j < 4; ++j) {
        float4 r = make_float4(acc[j][0], acc[j][1], acc[j][2], acc[j][3]);
        *(float4*)&h[(size_t)(nbase + ng * 4 + j) * 128 + fq * 4] = r;
    }
}

// ---- layer-2 gather + self-loop + bias + relu + fused batch-mean ----------
__global__ __launch_bounds__(256) void k_gather128(const int* __restrict__ rptr,
        const int* __restrict__ adj, const float* __restrict__ dis,
        const float* __restrict__ h, const float* __restrict__ bias,
        float* __restrict__ meanbuf) {
    __shared__ float sred[8][128];
    int bid  = (blockIdx.x & 7) * 1024 + (blockIdx.x >> 3);  // XCD swizzle, 8192 blocks
    int tid  = threadIdx.x;
    int g    = tid >> 5;
    int lane = tid & 31;
    int node = bid * 8 + g;
    int s = rptr[node], e = rptr[node + 1];
    float dn = dis[node];
    float4 acc = make_float4(0.f, 0.f, 0.f, 0.f);
    for (int base = s; base < e; base += 32) {
        int j = base + lane;
        int src = 0; float nd = 0.f;
        if (j < e) { src = adj[j]; nd = dis[src]; }
        int cnt = min(32, e - base);
        int k = 0;
        for (; k + 4 <= cnt; k += 4) {
            int   s0 = __shfl(src, k, 32),     s1 = __shfl(src, k + 1, 32);
            int   s2 = __shfl(src, k + 2, 32), s3 = __shfl(src, k + 3, 32);
            float n0 = __shfl(nd, k, 32),      n1 = __shfl(nd, k + 1, 32);
            float n2 = __shfl(nd, k + 2, 32),  n3 = __shfl(nd, k + 3, 32);
            float4 v0 = *(const float4*)&h[(size_t)s0 * 128 + lane * 4];
            float4 v1 = *(const float4*)&h[(size_t)s1 * 128 + lane * 4];
            float4 v2 = *(const float4*)&h[(size_t)s2 * 128 + lane * 4];
            float4 v3 = *(const float4*)&h[(size_t)s3 * 128 + lane * 4];
            float w0 = dn * n0, w1 = dn * n1, w2 = dn * n2, w3 = dn * n3;
            acc.x += w0*v0.x + w1*v1.x + w2*v2.x + w3*v3.x;
            acc.y += w0*v0.y + w1*v1.y + w2*v2.y + w3*v3.y;
            acc.z += w0*v0.z + w1*v1.z + w2*v2.z + w3*v3.z;
            acc.w += w0*v0.w + w1*v1.w + w2*v2.w + w3*v3.w;
        }
        for (; k < cnt; ++k) {
            int   sk = __shfl(src, k, 32);
            float nk = __shfl(nd, k, 32);
            float4 v = *(const float4*)&h[(size_t)sk * 128 + lane * 4];
            float wgt = dn * nk;
            acc.x += wgt * v.x; acc.y += wgt * v.y;
            acc.z += wgt * v.z; acc.w += wgt * v.w;
        }
    }
    float4 v = *(const float4*)&h[(size_t)node * 128 + lane * 4];
    float wgt = dn * dn;
    float4 bv = *(const float4*)&bias[lane * 4];
    acc.x = fmaxf(acc.x + wgt * v.x + bv.x, 0.f);
    acc.y = fmaxf(acc.y + wgt * v.y + bv.y, 0.f);
    acc.z = fmaxf(acc.z + wgt * v.z + bv.z, 0.f);
    acc.w = fmaxf(acc.w + wgt * v.w + bv.w, 0.f);
    *(float4*)&sred[g][lane * 4] = acc;
    __syncthreads();
    if (tid < 128) {
        float ssum = 0.f;
#pragma unroll
        for (int j = 0; j < 8; ++j) ssum += sred[j][tid];
        int sample = bid >> 6;            // 64 blocks (512 nodes) per sample
        unsafeAtomicAdd(&meanbuf[sample * 128 + tid], ssum * (1.0f / RR));
    }
}

// ---------------- fc: out[b] = mean[b] @ fw + fb ----------------
__global__ __launch_bounds__(128) void k_fc(const float* __restrict__ meanbuf,
        const float* __restrict__ fw, const float* __restrict__ fb,
        float* __restrict__ out) {
    __shared__ float sm[HID];
    int b = blockIdx.x, f = threadIdx.x;
    sm[f] = meanbuf[b * HID + f];
    __syncthreads();
    if (f < NOUT) {
        float s = fb[f];
#pragma unroll
        for (int c = 0; c < HID; ++c) s += sm[c] * fw[c * NOUT + f];
        out[b * NOUT + f] = s;
    }
}

extern "C" void kernel_launch(void* const* d_in, const int* in_sizes, int n_in,
                              void* d_out, int out_size, void* d_ws, size_t ws_size,
                              hipStream_t stream) {
    const float* x   = (const float*)d_in[0];
    const int*   ei  = (const int*)d_in[1];
    const float* c1w = (const float*)d_in[2];
    const float* c1b = (const float*)d_in[3];
    const float* c2w = (const float*)d_in[4];
    const float* c2b = (const float*)d_in[5];
    const float* g1w = (const float*)d_in[6];
    const float* g1b = (const float*)d_in[7];
    const float* g2w = (const float*)d_in[8];
    const float* g2b = (const float*)d_in[9];
    const float* fw  = (const float*)d_in[10];
    const float* fb  = (const float*)d_in[11];
    float* out = (float*)d_out;
    int E = in_sizes[1] / 2;   // 1048576

    char* ws = (char*)d_ws;
    float* out1    = (float*)(ws);                                   // 8 MB [B,16,1024] (convs only)
    int*   adj     = (int*)(ws);                                     // 4 MB [E] (after convs)
    float* dis     = (float*)(ws + (4u << 20));                      // 256 KB [N]
    int*   cnt     = (int*)(ws + (4u << 20) + (1u << 18));           // 256 KB [N]
    int*   rptr    = (int*)(ws + (4u << 20) + 2 * (1u << 18));       // 256 KB+4 [N+1]
    int*   cursor  = (int*)(ws + (4u << 20) + 3 * (1u << 18) + 4096);// 256 KB [N]
    float* nodes   = (float*)(ws + (8u << 20));                      // 8 MB [N,32]
    float* bufA    = (float*)(ws + (16u << 20));                     // 32 MB [N,128]
    float* agg32   = (float*)(ws + (48u << 20));                     // 8 MB [N,32]
    float* bufC    = (float*)(ws + (56u << 20));                     // 32 MB [N,128]
    float* meanbuf = (float*)(ws + (88u << 20));                     // 64 KB [B,128]

    // temporal convs first (out1 region reused by CSR afterwards)
    k_conv1<<<BB * 8, 256, 0, stream>>>(x, c1w, c1b, out1);
    k_conv2<<<BB * 4, 256, 0, stream>>>(out1, c2w, c2b, nodes);

    // CSR build + norms
    hipMemsetAsync(cnt, 0, (size_t)NN * 4, stream);
    hipMemsetAsync(cursor, 0, (size_t)NN * 4, stream);
    hipMemsetAsync(meanbuf, 0, (size_t)BB * HID * 4, stream);
    k_deg<<<(E + 255) / 256, 256, 0, stream>>>(ei, E, cnt);
    k_disv<<<NN / 256, 256, 0, stream>>>(cnt, dis);
    k_scan<<<1, 1024, 0, stream>>>(cnt, rptr);
    k_scatter<<<(E + 255) / 256, 256, 0, stream>>>(ei, E, rptr, cursor, adj);

    // GCN layer 1: aggregate 32-dim, then linear (+bias+relu)
    k_gather32<<<NN / 32, 256, 0, stream>>>(rptr, adj, dis, nodes, agg32);
    k_lin1<<<NN / 32, 256, 0, stream>>>(agg32, g1w, g1b, bufA);

    // GCN layer 2: linear, then aggregate (+bias+relu) fused with batch-mean
    k_lin2<<<NN / 32, 256, 0, stream>>>(bufA, g2w, bufC);
    k_gather128<<<NN / 8, 256, 0, stream>>>(rptr, adj, dis, bufC, g2b, meanbuf);

    // fc
    k_fc<<<BB, 128, 0, stream>>>(meanbuf, fw, fb, out);
}

// Round 4
// 212.362 us; speedup vs baseline: 17.7363x; 1.3670x over previous
//
#include <hip/hip_runtime.h>
#include <hip/hip_bf16.h>

#define BB   128
#define CIN  9
#define TT   2048
#define RR   512
#define NN   (BB*RR)     // 65536
#define HID  128
#define NOUT 12

// =======================================================================
// Fused conv1(9->16,k5,pad2)+relu+pool2 -> conv2(16->32,k5,pad2)+relu+pool2
// One block = one (sample, 128-node r-tile). conv1 recomputed with halo.
// Also zeroes cnt[512] and meanbuf[B*128] (used by later kernels).
// =======================================================================
__global__ __launch_bounds__(256) void k_convs(const float* __restrict__ x,
        const float* __restrict__ w1, const float* __restrict__ b1,
        const float* __restrict__ w2, const float* __restrict__ b2,
        float* __restrict__ nodes, int* __restrict__ cnt,
        float* __restrict__ meanbuf) {
    __shared__ float sx[CIN][524];     // x tile, g in [4r0-6, 4r0+518)
    __shared__ float s1[16][260];      // pooled conv1, p in [2r0-2, 2r0+258)
    __shared__ float sw1[16 * CIN * 5];
    __shared__ float sb1[16];
    __shared__ float sw2[32 * 16 * 5];
    __shared__ float sb2[32];
    int b  = blockIdx.x >> 2;
    int r0 = (blockIdx.x & 3) * 128;
    int tid = threadIdx.x;

    // side job: zero cnt (block 0) and meanbuf (blocks 0..63)
    if (blockIdx.x == 0) { cnt[tid] = 0; cnt[tid + 256] = 0; }
    if (blockIdx.x < 64) meanbuf[blockIdx.x * 256 + tid] = 0.f;

    // loads
    for (int idx = tid; idx < CIN * 524; idx += 256) {
        int c = idx / 524, j = idx - c * 524;
        int g = 4 * r0 - 6 + j;
        float v = 0.f;
        if (g >= 0 && g < TT) v = x[(b * CIN + c) * TT + g];
        sx[c][j] = v;
    }
    for (int idx = tid; idx < 16 * CIN * 5; idx += 256) sw1[idx] = w1[idx];
    for (int idx = tid; idx < 32 * 16 * 5; idx += 256) sw2[idx] = w2[idx];
    if (tid < 16) sb1[tid] = b1[tid];
    if (tid < 32) sb2[tid] = b2[tid];
    __syncthreads();

    // phase B: pooled conv1 into s1.  s1[c1][pp] = pooled1[p=2r0-2+pp]
    for (int idx = tid; idx < 16 * 260; idx += 256) {
        int c1 = idx / 260, pp = idx - c1 * 260;
        int p = 2 * r0 - 2 + pp;
        float val = 0.f;
        if (p >= 0 && p < 1024) {
            float a0 = sb1[c1], a1 = a0;
#pragma unroll
            for (int c = 0; c < CIN; ++c) {
                float xv[6];
#pragma unroll
                for (int k = 0; k < 6; ++k) xv[k] = sx[c][2 * pp + k];
#pragma unroll
                for (int k = 0; k < 5; ++k) {
                    float wv = sw1[(c1 * CIN + c) * 5 + k];
                    a0 += xv[k]     * wv;
                    a1 += xv[k + 1] * wv;
                }
            }
            val = fmaxf(fmaxf(a0, a1), 0.f);
        }
        s1[c1][pp] = val;
    }
    __syncthreads();

    // phase C: conv2 + relu + pool from s1 -> nodes[N,32]
    int rl   = tid & 127;
    int half = tid >> 7;    // 0/1 -> 16 channels each
    float acc0[16], acc1[16];
#pragma unroll
    for (int o = 0; o < 16; ++o) { float bv = sb2[half * 16 + o]; acc0[o] = bv; acc1[o] = bv; }
#pragma unroll
    for (int c = 0; c < 16; ++c) {
        float xv[6];
#pragma unroll
        for (int k = 0; k < 6; ++k) xv[k] = s1[c][2 * rl + k];
#pragma unroll
        for (int o = 0; o < 16; ++o) {
            int oo = half * 16 + o;
#pragma unroll
            for (int k = 0; k < 5; ++k) {
                float wv = sw2[(oo * 16 + c) * 5 + k];
                acc0[o] += xv[k]     * wv;
                acc1[o] += xv[k + 1] * wv;
            }
        }
    }
    int n = b * RR + r0 + rl;
#pragma unroll
    for (int o = 0; o < 16; ++o) {
        int oo = half * 16 + o;
        nodes[n * 32 + oo] = fmaxf(fmaxf(acc0[o], acc1[o]), 0.f);
    }
}

// =======================================================================
// Per-sample CSR build (graph is replicated: edges [0,es) with offsets b*R)
// =======================================================================
__global__ __launch_bounds__(256) void k_deg512(const int* __restrict__ ei, int E,
        int es, int* __restrict__ cnt) {
    int i = blockIdx.x * 256 + threadIdx.x;
    if (i < es) atomicAdd(&cnt[ei[E + i]], 1);
}

// 512-thread block: exclusive scan of cnt -> rptr, cursor copy, dis = rsqrt(deg+1)
__global__ __launch_bounds__(512) void k_scan512(const int* __restrict__ cnt, int es,
        int* __restrict__ rptr, int* __restrict__ cursor, float* __restrict__ dis) {
    __shared__ int sp[512];
    int t = threadIdx.x;
    int c = cnt[t];
    sp[t] = c;
    __syncthreads();
    for (int off = 1; off < 512; off <<= 1) {
        int v = sp[t];
        int add = (t >= off) ? sp[t - off] : 0;
        __syncthreads();
        sp[t] = v + add;
        __syncthreads();
    }
    int excl = sp[t] - c;
    rptr[t] = excl;
    cursor[t] = excl;
    if (t == 511) rptr[512] = es;
    dis[t] = rsqrtf((float)c + 1.0f);
}

__global__ __launch_bounds__(256) void k_scatter512(const int* __restrict__ ei, int E,
        int es, int* __restrict__ cursor, int* __restrict__ adj) {
    int i = blockIdx.x * 256 + threadIdx.x;
    if (i >= es) return;
    int row = ei[i];
    int col = ei[E + i];
    int pos = atomicAdd(&cursor[col], 1);
    adj[pos] = row;
}

// =======================================================================
// Fused layer-1: gather on 32-dim (agg commutes with W1) + lin1 + bias + relu
// Block = 32 consecutive nodes (same sample). 8 lanes/node for gather.
// =======================================================================
__global__ __launch_bounds__(256) void k_gl1(const int* __restrict__ rptr,
        const int* __restrict__ adj, const float* __restrict__ dis,
        const float* __restrict__ nodes, const float* __restrict__ w,
        const float* __restrict__ bias, float* __restrict__ h) {
    __shared__ float srow[32][32];
    __shared__ float sw[32 * 128];
    int bid = (blockIdx.x & 7) * 256 + (blockIdx.x >> 3);   // XCD swizzle, 2048
    int tid = threadIdx.x;
    int nbase = bid * 32;
    int b = nbase >> 9;
    const float* hb = nodes + (size_t)b * RR * 32;          // sample base

    {   // weights -> LDS (1024 float4)
        const float4* src = (const float4*)w;
        float4* dst = (float4*)sw;
#pragma unroll
        for (int i = 0; i < 4; ++i) dst[tid + i * 256] = src[tid + i * 256];
    }

    int ln   = tid >> 3;            // local node 0..31
    int lane = tid & 7;
    int r = (nbase & 511) + ln;     // node index within sample
    int s = rptr[r], e = rptr[r + 1];
    float dn = dis[r];
    float4 acc = make_float4(0.f, 0.f, 0.f, 0.f);
    for (int base = s; base < e; base += 8) {
        int j = base + lane;
        int src = 0; float nd = 0.f;
        if (j < e) { src = adj[j]; nd = dis[src]; }
        int cnt = min(8, e - base);
        int k = 0;
        for (; k + 4 <= cnt; k += 4) {
            int   s0 = __shfl(src, k, 8),     s1 = __shfl(src, k + 1, 8);
            int   s2 = __shfl(src, k + 2, 8), s3 = __shfl(src, k + 3, 8);
            float n0 = __shfl(nd, k, 8),      n1 = __shfl(nd, k + 1, 8);
            float n2 = __shfl(nd, k + 2, 8),  n3 = __shfl(nd, k + 3, 8);
            float4 v0 = *(const float4*)&hb[(size_t)s0 * 32 + lane * 4];
            float4 v1 = *(const float4*)&hb[(size_t)s1 * 32 + lane * 4];
            float4 v2 = *(const float4*)&hb[(size_t)s2 * 32 + lane * 4];
            float4 v3 = *(const float4*)&hb[(size_t)s3 * 32 + lane * 4];
            float w0 = dn * n0, w1 = dn * n1, w2 = dn * n2, w3 = dn * n3;
            acc.x += w0*v0.x + w1*v1.x + w2*v2.x + w3*v3.x;
            acc.y += w0*v0.y + w1*v1.y + w2*v2.y + w3*v3.y;
            acc.z += w0*v0.z + w1*v1.z + w2*v2.z + w3*v3.z;
            acc.w += w0*v0.w + w1*v1.w + w2*v2.w + w3*v3.w;
        }
        for (; k < cnt; ++k) {
            int   sk = __shfl(src, k, 8);
            float nk = __shfl(nd, k, 8);
            float4 v = *(const float4*)&hb[(size_t)sk * 32 + lane * 4];
            float wgt = dn * nk;
            acc.x += wgt * v.x; acc.y += wgt * v.y;
            acc.z += wgt * v.z; acc.w += wgt * v.w;
        }
    }
    {   // self loop
        float4 v = *(const float4*)&hb[(size_t)r * 32 + lane * 4];
        float wgt = dn * dn;
        acc.x += wgt * v.x; acc.y += wgt * v.y;
        acc.z += wgt * v.z; acc.w += wgt * v.w;
    }
    *(float4*)&srow[ln][lane * 4] = acc;
    __syncthreads();

    // lin1: srow[32x32] @ sw[32x128] + bias, relu
    int fq = tid & 31;
    int ng = tid >> 5;
    float a[4][4];
#pragma unroll
    for (int j = 0; j < 4; ++j)
#pragma unroll
        for (int q = 0; q < 4; ++q) a[j][q] = 0.f;
#pragma unroll
    for (int c = 0; c < 32; ++c) {
        float4 wv = *(const float4*)&sw[c * 128 + fq * 4];
#pragma unroll
        for (int j = 0; j < 4; ++j) {
            float xc = srow[ng * 4 + j][c];
            a[j][0] += xc * wv.x; a[j][1] += xc * wv.y;
            a[j][2] += xc * wv.z; a[j][3] += xc * wv.w;
        }
    }
    float4 bv = *(const float4*)&bias[fq * 4];
#pragma unroll
    for (int j = 0; j < 4; ++j) {
        float4 rr = make_float4(fmaxf(a[j][0] + bv.x, 0.f),
                                fmaxf(a[j][1] + bv.y, 0.f),
                                fmaxf(a[j][2] + bv.z, 0.f),
                                fmaxf(a[j][3] + bv.w, 0.f));
        *(float4*)&h[(size_t)(nbase + ng * 4 + j) * 128 + fq * 4] = rr;
    }
}

// ---------------- lin2: h[N,128] = g[N,128] @ W[128,128] ----------------
__global__ __launch_bounds__(256) void k_lin2(const float* __restrict__ g,
        const float* __restrict__ w, float* __restrict__ h) {
    __shared__ float srow[32 * 128];
    __shared__ float swc[64 * 128];
    int tid = threadIdx.x;
    int nbase = blockIdx.x * 32;
    {
        const float4* src = (const float4*)(g + (size_t)nbase * 128);
        float4* dst = (float4*)srow;
#pragma unroll
        for (int i = 0; i < 4; ++i) dst[tid + i * 256] = src[tid + i * 256];
    }
    int fq = tid & 31;
    int ng = tid >> 5;
    float acc[4][4];
#pragma unroll
    for (int j = 0; j < 4; ++j)
#pragma unroll
        for (int q = 0; q < 4; ++q) acc[j][q] = 0.f;

    for (int ch = 0; ch < 2; ++ch) {
        if (ch) __syncthreads();
        {
            const float4* src = (const float4*)(w + ch * 64 * 128);
            float4* dst = (float4*)swc;
#pragma unroll
            for (int i = 0; i < 8; ++i) dst[tid + i * 256] = src[tid + i * 256];
        }
        __syncthreads();
        int c0 = ch * 64;
#pragma unroll
        for (int c = 0; c < 64; ++c) {
            float4 wv = *(const float4*)&swc[c * 128 + fq * 4];
#pragma unroll
            for (int j = 0; j < 4; ++j) {
                float xc = srow[(ng * 4 + j) * 128 + c0 + c];
                acc[j][0] += xc * wv.x; acc[j][1] += xc * wv.y;
                acc[j][2] += xc * wv.z; acc[j][3] += xc * wv.w;
            }
        }
    }
#pragma unroll
    for (int j = 0; j < 4; ++j) {
        float4 r = make_float4(acc[j][0], acc[j][1], acc[j][2], acc[j][3]);
        *(float4*)&h[(size_t)(nbase + ng * 4 + j) * 128 + fq * 4] = r;
    }
}

// ---- layer-2 gather + self-loop + bias + relu + fused batch-mean ----------
__global__ __launch_bounds__(256) void k_gather128(const int* __restrict__ rptr,
        const int* __restrict__ adj, const float* __restrict__ dis,
        const float* __restrict__ h, const float* __restrict__ bias,
        float* __restrict__ meanbuf) {
    __shared__ float sred[8][128];
    int bid  = (blockIdx.x & 7) * 1024 + (blockIdx.x >> 3);  // XCD swizzle, 8192
    int tid  = threadIdx.x;
    int g    = tid >> 5;
    int lane = tid & 31;
    int node = bid * 8 + g;
    int b = node >> 9;
    int r = node & 511;
    const float* hb = h + (size_t)b * RR * 128;              // sample base
    int s = rptr[r], e = rptr[r + 1];
    float dn = dis[r];
    float4 acc = make_float4(0.f, 0.f, 0.f, 0.f);
    for (int base = s; base < e; base += 32) {
        int j = base + lane;
        int src = 0; float nd = 0.f;
        if (j < e) { src = adj[j]; nd = dis[src]; }
        int cnt = min(32, e - base);
        int k = 0;
        for (; k + 4 <= cnt; k += 4) {
            int   s0 = __shfl(src, k, 32),     s1 = __shfl(src, k + 1, 32);
            int   s2 = __shfl(src, k + 2, 32), s3 = __shfl(src, k + 3, 32);
            float n0 = __shfl(nd, k, 32),      n1 = __shfl(nd, k + 1, 32);
            float n2 = __shfl(nd, k + 2, 32),  n3 = __shfl(nd, k + 3, 32);
            float4 v0 = *(const float4*)&hb[(size_t)s0 * 128 + lane * 4];
            float4 v1 = *(const float4*)&hb[(size_t)s1 * 128 + lane * 4];
            float4 v2 = *(const float4*)&hb[(size_t)s2 * 128 + lane * 4];
            float4 v3 = *(const float4*)&hb[(size_t)s3 * 128 + lane * 4];
            float w0 = dn * n0, w1 = dn * n1, w2 = dn * n2, w3 = dn * n3;
            acc.x += w0*v0.x + w1*v1.x + w2*v2.x + w3*v3.x;
            acc.y += w0*v0.y + w1*v1.y + w2*v2.y + w3*v3.y;
            acc.z += w0*v0.z + w1*v1.z + w2*v2.z + w3*v3.z;
            acc.w += w0*v0.w + w1*v1.w + w2*v2.w + w3*v3.w;
        }
        for (; k < cnt; ++k) {
            int   sk = __shfl(src, k, 32);
            float nk = __shfl(nd, k, 32);
            float4 v = *(const float4*)&hb[(size_t)sk * 128 + lane * 4];
            float wgt = dn * nk;
            acc.x += wgt * v.x; acc.y += wgt * v.y;
            acc.z += wgt * v.z; acc.w += wgt * v.w;
        }
    }
    float4 v = *(const float4*)&hb[(size_t)r * 128 + lane * 4];
    float wgt = dn * dn;
    float4 bv = *(const float4*)&bias[lane * 4];
    acc.x = fmaxf(acc.x + wgt * v.x + bv.x, 0.f);
    acc.y = fmaxf(acc.y + wgt * v.y + bv.y, 0.f);
    acc.z = fmaxf(acc.z + wgt * v.z + bv.z, 0.f);
    acc.w = fmaxf(acc.w + wgt * v.w + bv.w, 0.f);
    *(float4*)&sred[g][lane * 4] = acc;
    __syncthreads();
    if (tid < 128) {
        float ssum = 0.f;
#pragma unroll
        for (int j = 0; j < 8; ++j) ssum += sred[j][tid];
        int sample = bid >> 6;            // 64 blocks (512 nodes) per sample
        unsafeAtomicAdd(&meanbuf[sample * 128 + tid], ssum * (1.0f / RR));
    }
}

// ---------------- fc: out[b] = mean[b] @ fw + fb ----------------
__global__ __launch_bounds__(128) void k_fc(const float* __restrict__ meanbuf,
        const float* __restrict__ fw, const float* __restrict__ fb,
        float* __restrict__ out) {
    __shared__ float sm[HID];
    int b = blockIdx.x, f = threadIdx.x;
    sm[f] = meanbuf[b * HID + f];
    __syncthreads();
    if (f < NOUT) {
        float s = fb[f];
#pragma unroll
        for (int c = 0; c < HID; ++c) s += sm[c] * fw[c * NOUT + f];
        out[b * NOUT + f] = s;
    }
}

extern "C" void kernel_launch(void* const* d_in, const int* in_sizes, int n_in,
                              void* d_out, int out_size, void* d_ws, size_t ws_size,
                              hipStream_t stream) {
    const float* x   = (const float*)d_in[0];
    const int*   ei  = (const int*)d_in[1];
    const float* c1w = (const float*)d_in[2];
    const float* c1b = (const float*)d_in[3];
    const float* c2w = (const float*)d_in[4];
    const float* c2b = (const float*)d_in[5];
    const float* g1w = (const float*)d_in[6];
    const float* g1b = (const float*)d_in[7];
    const float* g2w = (const float*)d_in[8];
    const float* g2b = (const float*)d_in[9];
    const float* fw  = (const float*)d_in[10];
    const float* fb  = (const float*)d_in[11];
    float* out = (float*)d_out;
    int E  = in_sizes[1] / 2;   // total edges (1048576)
    int es = E / BB;            // edges per sample graph (8192)

    char* ws = (char*)d_ws;
    float* nodes   = (float*)(ws);                       // 8 MB  [N,32]
    float* bufA    = (float*)(ws + (8u  << 20));         // 32 MB [N,128]
    float* bufC    = (float*)(ws + (40u << 20));         // 32 MB [N,128]
    int*   cnt     = (int*)  (ws + (72u << 20));         // 2 KB  [512]
    int*   rptr    = (int*)  (ws + (72u << 20) + 4096);  // 2 KB+4 [513]
    int*   cursor  = (int*)  (ws + (72u << 20) + 8192);  // 2 KB  [512]
    float* dis     = (float*)(ws + (72u << 20) + 12288); // 2 KB  [512]
    int*   adj     = (int*)  (ws + (72u << 20) + 16384); // 32 KB [es]
    float* meanbuf = (float*)(ws + (73u << 20));         // 64 KB [B,128]

    // fused temporal convs (also zeroes cnt + meanbuf)
    k_convs<<<BB * 4, 256, 0, stream>>>(x, c1w, c1b, c2w, c2b, nodes, cnt, meanbuf);

    // per-sample CSR (graph replicated across batch with offset b*R)
    k_deg512<<<(es + 255) / 256, 256, 0, stream>>>(ei, E, es, cnt);
    k_scan512<<<1, 512, 0, stream>>>(cnt, es, rptr, cursor, dis);
    k_scatter512<<<(es + 255) / 256, 256, 0, stream>>>(ei, E, es, cursor, adj);

    // GCN layer 1: fused gather(32-dim) + linear + bias + relu
    k_gl1<<<NN / 32, 256, 0, stream>>>(rptr, adj, dis, nodes, g1w, g1b, bufA);

    // GCN layer 2: linear, then gather (+bias+relu) fused with batch-mean
    k_lin2<<<NN / 32, 256, 0, stream>>>(bufA, g2w, bufC);
    k_gather128<<<NN / 8, 256, 0, stream>>>(rptr, adj, dis, bufC, g2b, meanbuf);

    // fc
    k_fc<<<BB, 128, 0, stream>>>(meanbuf, fw, fb, out);
}

// Round 5
// 200.698 us; speedup vs baseline: 18.7670x; 1.0581x over previous
//
#include <hip/hip_runtime.h>
#include <hip/hip_bf16.h>

#define BB   128
#define CIN  9
#define TT   2048
#define RR   512
#define NN   (BB*RR)     // 65536
#define HID  128
#define NOUT 12

typedef __attribute__((ext_vector_type(8))) short short8;
typedef __attribute__((ext_vector_type(4))) float f32x4;

static __device__ inline unsigned short f2bf(float f) {       // RNE f32->bf16
    unsigned int u = __float_as_uint(f);
    unsigned int r = (u + 0x7fffu + ((u >> 16) & 1u)) >> 16;
    return (unsigned short)r;
}
static __device__ inline float bf2f(unsigned short u) {
    return __uint_as_float(((unsigned int)u) << 16);
}

// =======================================================================
// Fused conv1(9->16,k5,pad2)+relu+pool2 -> conv2(16->32,k5,pad2)+relu+pool2
// Also zeroes meanbuf[B*128].
// =======================================================================
__global__ __launch_bounds__(256) void k_convs(const float* __restrict__ x,
        const float* __restrict__ w1, const float* __restrict__ b1,
        const float* __restrict__ w2, const float* __restrict__ b2,
        float* __restrict__ nodes, float* __restrict__ meanbuf) {
    __shared__ float sx[CIN][524];
    __shared__ float s1[16][260];
    __shared__ float sw1[16 * CIN * 5];
    __shared__ float sb1[16];
    __shared__ float sw2[32 * 16 * 5];
    __shared__ float sb2[32];
    int b  = blockIdx.x >> 2;
    int r0 = (blockIdx.x & 3) * 128;
    int tid = threadIdx.x;

    if (blockIdx.x < 64) meanbuf[blockIdx.x * 256 + tid] = 0.f;

    for (int idx = tid; idx < CIN * 524; idx += 256) {
        int c = idx / 524, j = idx - c * 524;
        int g = 4 * r0 - 6 + j;
        float v = 0.f;
        if (g >= 0 && g < TT) v = x[(b * CIN + c) * TT + g];
        sx[c][j] = v;
    }
    for (int idx = tid; idx < 16 * CIN * 5; idx += 256) sw1[idx] = w1[idx];
    for (int idx = tid; idx < 32 * 16 * 5; idx += 256) sw2[idx] = w2[idx];
    if (tid < 16) sb1[tid] = b1[tid];
    if (tid < 32) sb2[tid] = b2[tid];
    __syncthreads();

    // pooled conv1 into s1
    for (int idx = tid; idx < 16 * 260; idx += 256) {
        int c1 = idx / 260, pp = idx - c1 * 260;
        int p = 2 * r0 - 2 + pp;
        float val = 0.f;
        if (p >= 0 && p < 1024) {
            float a0 = sb1[c1], a1 = a0;
#pragma unroll
            for (int c = 0; c < CIN; ++c) {
                float xv[6];
#pragma unroll
                for (int k = 0; k < 6; ++k) xv[k] = sx[c][2 * pp + k];
#pragma unroll
                for (int k = 0; k < 5; ++k) {
                    float wv = sw1[(c1 * CIN + c) * 5 + k];
                    a0 += xv[k]     * wv;
                    a1 += xv[k + 1] * wv;
                }
            }
            val = fmaxf(fmaxf(a0, a1), 0.f);
        }
        s1[c1][pp] = val;
    }
    __syncthreads();

    // conv2 + relu + pool -> nodes[N,32] (f32)
    int rl   = tid & 127;
    int half = tid >> 7;
    float acc0[16], acc1[16];
#pragma unroll
    for (int o = 0; o < 16; ++o) { float bv = sb2[half * 16 + o]; acc0[o] = bv; acc1[o] = bv; }
#pragma unroll
    for (int c = 0; c < 16; ++c) {
        float xv[6];
#pragma unroll
        for (int k = 0; k < 6; ++k) xv[k] = s1[c][2 * rl + k];
#pragma unroll
        for (int o = 0; o < 16; ++o) {
            int oo = half * 16 + o;
#pragma unroll
            for (int k = 0; k < 5; ++k) {
                float wv = sw2[(oo * 16 + c) * 5 + k];
                acc0[o] += xv[k]     * wv;
                acc1[o] += xv[k + 1] * wv;
            }
        }
    }
    int n = b * RR + r0 + rl;
#pragma unroll
    for (int o = 0; o < 16; ++o) {
        int oo = half * 16 + o;
        nodes[n * 32 + oo] = fmaxf(fmaxf(acc0[o], acc1[o]), 0.f);
    }
}

// =======================================================================
// Single-block CSR build for the per-sample graph (LDS counts/scan/cursors)
// =======================================================================
__global__ __launch_bounds__(512) void k_graph(const int* __restrict__ ei, int E,
        int es, int* __restrict__ rptr, float* __restrict__ dis,
        int* __restrict__ adj) {
    __shared__ int lcnt[512];
    __shared__ int sp[512];
    __shared__ int lcur[512];
    int t = threadIdx.x;
    lcnt[t] = 0;
    __syncthreads();
    for (int i = t; i < es; i += 512) atomicAdd(&lcnt[ei[E + i]], 1);
    __syncthreads();
    int c = lcnt[t];
    sp[t] = c;
    __syncthreads();
    for (int off = 1; off < 512; off <<= 1) {
        int v = sp[t];
        int add = (t >= off) ? sp[t - off] : 0;
        __syncthreads();
        sp[t] = v + add;
        __syncthreads();
    }
    int excl = sp[t] - c;
    rptr[t] = excl;
    if (t == 511) rptr[512] = es;
    dis[t] = rsqrtf((float)c + 1.0f);
    lcur[t] = excl;
    __syncthreads();
    for (int i = t; i < es; i += 512) {
        int row = ei[i], col = ei[E + i];
        int pos = atomicAdd(&lcur[col], 1);
        adj[pos] = row;
    }
}

// =======================================================================
// Fused layer-1: gather on 32-dim + lin1 + bias + relu -> h1 (bf16)
// =======================================================================
__global__ __launch_bounds__(256) void k_gl1(const int* __restrict__ rptr,
        const int* __restrict__ adj, const float* __restrict__ dis,
        const float* __restrict__ nodes, const float* __restrict__ w,
        const float* __restrict__ bias, unsigned short* __restrict__ h16) {
    __shared__ float srow[32][32];
    __shared__ float sw[32 * 128];
    int bid = (blockIdx.x & 7) * 256 + (blockIdx.x >> 3);   // XCD swizzle, 2048
    int tid = threadIdx.x;
    int nbase = bid * 32;
    int b = nbase >> 9;
    const float* hb = nodes + (size_t)b * RR * 32;

    {   // weights -> LDS
        const float4* src = (const float4*)w;
        float4* dst = (float4*)sw;
#pragma unroll
        for (int i = 0; i < 4; ++i) dst[tid + i * 256] = src[tid + i * 256];
    }

    int ln   = tid >> 3;
    int lane = tid & 7;
    int r = (nbase & 511) + ln;
    int s = rptr[r], e = rptr[r + 1];
    float dn = dis[r];
    float4 acc = make_float4(0.f, 0.f, 0.f, 0.f);
    for (int base = s; base < e; base += 8) {
        int j = base + lane;
        int src = 0; float nd = 0.f;
        if (j < e) { src = adj[j]; nd = dis[src]; }
        int cnt = min(8, e - base);
        int k = 0;
        for (; k + 4 <= cnt; k += 4) {
            int   s0 = __shfl(src, k, 8),     s1 = __shfl(src, k + 1, 8);
            int   s2 = __shfl(src, k + 2, 8), s3 = __shfl(src, k + 3, 8);
            float n0 = __shfl(nd, k, 8),      n1 = __shfl(nd, k + 1, 8);
            float n2 = __shfl(nd, k + 2, 8),  n3 = __shfl(nd, k + 3, 8);
            float4 v0 = *(const float4*)&hb[(size_t)s0 * 32 + lane * 4];
            float4 v1 = *(const float4*)&hb[(size_t)s1 * 32 + lane * 4];
            float4 v2 = *(const float4*)&hb[(size_t)s2 * 32 + lane * 4];
            float4 v3 = *(const float4*)&hb[(size_t)s3 * 32 + lane * 4];
            float w0 = dn * n0, w1 = dn * n1, w2 = dn * n2, w3 = dn * n3;
            acc.x += w0*v0.x + w1*v1.x + w2*v2.x + w3*v3.x;
            acc.y += w0*v0.y + w1*v1.y + w2*v2.y + w3*v3.y;
            acc.z += w0*v0.z + w1*v1.z + w2*v2.z + w3*v3.z;
            acc.w += w0*v0.w + w1*v1.w + w2*v2.w + w3*v3.w;
        }
        for (; k < cnt; ++k) {
            int   sk = __shfl(src, k, 8);
            float nk = __shfl(nd, k, 8);
            float4 v = *(const float4*)&hb[(size_t)sk * 32 + lane * 4];
            float wgt = dn * nk;
            acc.x += wgt * v.x; acc.y += wgt * v.y;
            acc.z += wgt * v.z; acc.w += wgt * v.w;
        }
    }
    {
        float4 v = *(const float4*)&hb[(size_t)r * 32 + lane * 4];
        float wgt = dn * dn;
        acc.x += wgt * v.x; acc.y += wgt * v.y;
        acc.z += wgt * v.z; acc.w += wgt * v.w;
    }
    *(float4*)&srow[ln][lane * 4] = acc;
    __syncthreads();

    int fq = tid & 31;
    int ng = tid >> 5;
    float a[4][4];
#pragma unroll
    for (int j = 0; j < 4; ++j)
#pragma unroll
        for (int q = 0; q < 4; ++q) a[j][q] = 0.f;
#pragma unroll
    for (int c = 0; c < 32; ++c) {
        float4 wv = *(const float4*)&sw[c * 128 + fq * 4];
#pragma unroll
        for (int j = 0; j < 4; ++j) {
            float xc = srow[ng * 4 + j][c];
            a[j][0] += xc * wv.x; a[j][1] += xc * wv.y;
            a[j][2] += xc * wv.z; a[j][3] += xc * wv.w;
        }
    }
    float4 bv = *(const float4*)&bias[fq * 4];
#pragma unroll
    for (int j = 0; j < 4; ++j) {
        ushort4 o;
        o.x = f2bf(fmaxf(a[j][0] + bv.x, 0.f));
        o.y = f2bf(fmaxf(a[j][1] + bv.y, 0.f));
        o.z = f2bf(fmaxf(a[j][2] + bv.z, 0.f));
        o.w = f2bf(fmaxf(a[j][3] + bv.w, 0.f));
        *(ushort4*)&h16[(size_t)(nbase + ng * 4 + j) * 128 + fq * 4] = o;
    }
}

// =======================================================================
// lin2 via MFMA bf16: h2[N,128] = h1[N,128] @ W[128,128]   (bf16 in/out)
// 64 nodes/block, 4 waves; wave w does rows w*16..w*16+15 x all 128 cols.
// LDS padded to 136 bf16/row -> even bank spread for ds_read_b128.
// =======================================================================
__global__ __launch_bounds__(256) void k_lin2(const unsigned short* __restrict__ g16,
        const float* __restrict__ w, unsigned short* __restrict__ h16) {
    __shared__ unsigned short srow[64][136];
    __shared__ unsigned short swT[128][136];
    int tid = threadIdx.x;
    int nbase = blockIdx.x * 64;

    {   // stage A rows (64x128 bf16), coalesced 8B loads
        const ushort4* src = (const ushort4*)(g16 + (size_t)nbase * 128);
#pragma unroll
        for (int i = 0; i < 8; ++i) {
            int idx = tid + i * 256;     // ushort4 index, 2048 total
            int row = idx >> 5, col4 = idx & 31;
            ushort4 v = src[idx];
            *(ushort4*)&srow[row][col4 * 4] = v;
        }
    }
    {   // stage W^T as bf16: swT[f][c] = bf16(w[c][f])
        for (int i = 0; i < 64; ++i) {
            int idx = i * 256 + tid;     // 16384 elements
            int c = idx >> 7, f = idx & 127;
            swT[f][c] = f2bf(w[idx]);
        }
    }
    __syncthreads();

    int wv  = tid >> 6;          // wave 0..3
    int lane = tid & 63;
    int m0 = wv * 16;
    int l15 = lane & 15;
    int quad = lane >> 4;
    f32x4 acc[8];
#pragma unroll
    for (int nt = 0; nt < 8; ++nt) acc[nt] = (f32x4){0.f, 0.f, 0.f, 0.f};
#pragma unroll
    for (int kc = 0; kc < 4; ++kc) {
        int k0 = kc * 32 + quad * 8;
        short8 a = *(const short8*)&srow[m0 + l15][k0];
#pragma unroll
        for (int nt = 0; nt < 8; ++nt) {
            short8 b = *(const short8*)&swT[nt * 16 + l15][k0];
            acc[nt] = __builtin_amdgcn_mfma_f32_16x16x32_bf16(a, b, acc[nt], 0, 0, 0);
        }
    }
#pragma unroll
    for (int nt = 0; nt < 8; ++nt) {
#pragma unroll
        for (int r = 0; r < 4; ++r) {
            int row = m0 + quad * 4 + r;
            int col = nt * 16 + l15;
            h16[(size_t)(nbase + row) * 128 + col] = f2bf(acc[nt][r]);
        }
    }
}

// ---- layer-2 gather (bf16 h) + self-loop + bias + relu + fused batch-mean --
__global__ __launch_bounds__(256) void k_gather128(const int* __restrict__ rptr,
        const int* __restrict__ adj, const float* __restrict__ dis,
        const unsigned short* __restrict__ h, const float* __restrict__ bias,
        float* __restrict__ meanbuf) {
    __shared__ float sred[8][128];
    int bid  = (blockIdx.x & 7) * 1024 + (blockIdx.x >> 3);  // XCD swizzle, 8192
    int tid  = threadIdx.x;
    int g    = tid >> 5;
    int lane = tid & 31;
    int node = bid * 8 + g;
    int b = node >> 9;
    int r = node & 511;
    const unsigned short* hb = h + (size_t)b * RR * 128;
    int s = rptr[r], e = rptr[r + 1];
    float dn = dis[r];
    float4 acc = make_float4(0.f, 0.f, 0.f, 0.f);
    for (int base = s; base < e; base += 32) {
        int j = base + lane;
        int src = 0; float nd = 0.f;
        if (j < e) { src = adj[j]; nd = dis[src]; }
        int cnt = min(32, e - base);
        int k = 0;
        for (; k + 4 <= cnt; k += 4) {
            int   s0 = __shfl(src, k, 32),     s1 = __shfl(src, k + 1, 32);
            int   s2 = __shfl(src, k + 2, 32), s3 = __shfl(src, k + 3, 32);
            float n0 = __shfl(nd, k, 32),      n1 = __shfl(nd, k + 1, 32);
            float n2 = __shfl(nd, k + 2, 32),  n3 = __shfl(nd, k + 3, 32);
            ushort4 u0 = *(const ushort4*)&hb[(size_t)s0 * 128 + lane * 4];
            ushort4 u1 = *(const ushort4*)&hb[(size_t)s1 * 128 + lane * 4];
            ushort4 u2 = *(const ushort4*)&hb[(size_t)s2 * 128 + lane * 4];
            ushort4 u3 = *(const ushort4*)&hb[(size_t)s3 * 128 + lane * 4];
            float w0 = dn * n0, w1 = dn * n1, w2 = dn * n2, w3 = dn * n3;
            acc.x += w0*bf2f(u0.x) + w1*bf2f(u1.x) + w2*bf2f(u2.x) + w3*bf2f(u3.x);
            acc.y += w0*bf2f(u0.y) + w1*bf2f(u1.y) + w2*bf2f(u2.y) + w3*bf2f(u3.y);
            acc.z += w0*bf2f(u0.z) + w1*bf2f(u1.z) + w2*bf2f(u2.z) + w3*bf2f(u3.z);
            acc.w += w0*bf2f(u0.w) + w1*bf2f(u1.w) + w2*bf2f(u2.w) + w3*bf2f(u3.w);
        }
        for (; k < cnt; ++k) {
            int   sk = __shfl(src, k, 32);
            float nk = __shfl(nd, k, 32);
            ushort4 u = *(const ushort4*)&hb[(size_t)sk * 128 + lane * 4];
            float wgt = dn * nk;
            acc.x += wgt * bf2f(u.x); acc.y += wgt * bf2f(u.y);
            acc.z += wgt * bf2f(u.z); acc.w += wgt * bf2f(u.w);
        }
    }
    ushort4 u = *(const ushort4*)&hb[(size_t)r * 128 + lane * 4];
    float wgt = dn * dn;
    float4 bv = *(const float4*)&bias[lane * 4];
    acc.x = fmaxf(acc.x + wgt * bf2f(u.x) + bv.x, 0.f);
    acc.y = fmaxf(acc.y + wgt * bf2f(u.y) + bv.y, 0.f);
    acc.z = fmaxf(acc.z + wgt * bf2f(u.z) + bv.z, 0.f);
    acc.w = fmaxf(acc.w + wgt * bf2f(u.w) + bv.w, 0.f);
    *(float4*)&sred[g][lane * 4] = acc;
    __syncthreads();
    if (tid < 128) {
        float ssum = 0.f;
#pragma unroll
        for (int j = 0; j < 8; ++j) ssum += sred[j][tid];
        int sample = bid >> 6;
        unsafeAtomicAdd(&meanbuf[sample * 128 + tid], ssum * (1.0f / RR));
    }
}

// ---------------- fc: out[b] = mean[b] @ fw + fb ----------------
__global__ __launch_bounds__(128) void k_fc(const float* __restrict__ meanbuf,
        const float* __restrict__ fw, const float* __restrict__ fb,
        float* __restrict__ out) {
    __shared__ float sm[HID];
    int b = blockIdx.x, f = threadIdx.x;
    sm[f] = meanbuf[b * HID + f];
    __syncthreads();
    if (f < NOUT) {
        float s = fb[f];
#pragma unroll
        for (int c = 0; c < HID; ++c) s += sm[c] * fw[c * NOUT + f];
        out[b * NOUT + f] = s;
    }
}

extern "C" void kernel_launch(void* const* d_in, const int* in_sizes, int n_in,
                              void* d_out, int out_size, void* d_ws, size_t ws_size,
                              hipStream_t stream) {
    const float* x   = (const float*)d_in[0];
    const int*   ei  = (const int*)d_in[1];
    const float* c1w = (const float*)d_in[2];
    const float* c1b = (const float*)d_in[3];
    const float* c2w = (const float*)d_in[4];
    const float* c2b = (const float*)d_in[5];
    const float* g1w = (const float*)d_in[6];
    const float* g1b = (const float*)d_in[7];
    const float* g2w = (const float*)d_in[8];
    const float* g2b = (const float*)d_in[9];
    const float* fw  = (const float*)d_in[10];
    const float* fb  = (const float*)d_in[11];
    float* out = (float*)d_out;
    int E  = in_sizes[1] / 2;   // total edges (1048576)
    int es = E / BB;            // edges per sample graph (8192)

    char* ws = (char*)d_ws;
    float*          nodes   = (float*)(ws);                        // 8 MB  [N,32] f32
    unsigned short* bufA16  = (unsigned short*)(ws + (8u  << 20)); // 16 MB [N,128] bf16
    unsigned short* bufC16  = (unsigned short*)(ws + (24u << 20)); // 16 MB [N,128] bf16
    int*   rptr    = (int*)  (ws + (40u << 20));                   // [513]
    float* dis     = (float*)(ws + (40u << 20) + 4096);            // [512]
    int*   adj     = (int*)  (ws + (40u << 20) + 8192);            // 32 KB [es]
    float* meanbuf = (float*)(ws + (41u << 20));                   // 64 KB [B,128]

    // fused temporal convs (also zeroes meanbuf)
    k_convs<<<BB * 4, 256, 0, stream>>>(x, c1w, c1b, c2w, c2b, nodes, meanbuf);

    // per-sample CSR in one block
    k_graph<<<1, 512, 0, stream>>>(ei, E, es, rptr, dis, adj);

    // GCN layer 1: fused gather(32-dim) + linear + bias + relu -> bf16
    k_gl1<<<NN / 32, 256, 0, stream>>>(rptr, adj, dis, nodes, g1w, g1b, bufA16);

    // GCN layer 2: MFMA linear (bf16), then gather (+bias+relu) + batch-mean
    k_lin2<<<NN / 64, 256, 0, stream>>>(bufA16, g2w, bufC16);
    k_gather128<<<NN / 8, 256, 0, stream>>>(rptr, adj, dis, bufC16, g2b, meanbuf);

    // fc
    k_fc<<<BB, 128, 0, stream>>>(meanbuf, fw, fb, out);
}

// Round 6
// 176.012 us; speedup vs baseline: 21.3992x; 1.1403x over previous
//
#include <hip/hip_runtime.h>
#include <hip/hip_bf16.h>

#define BB   128
#define CIN  9
#define TT   2048
#define RR   512
#define NN   (BB*RR)     // 65536
#define HID  128
#define NOUT 12

typedef __attribute__((ext_vector_type(8))) short short8;
typedef __attribute__((ext_vector_type(4))) float f32x4;

static __device__ inline unsigned short f2bf(float f) {       // RNE f32->bf16
    unsigned int u = __float_as_uint(f);
    unsigned int r = (u + 0x7fffu + ((u >> 16) & 1u)) >> 16;
    return (unsigned short)r;
}
static __device__ inline float bf2f(unsigned short u) {
    return __uint_as_float(((unsigned int)u) << 16);
}

// =======================================================================
// Fused conv1+relu+pool2 -> conv2+relu+pool2  (blocks 0..1023, 64 nodes each)
// + per-sample CSR graph build               (block 1024, runs concurrently)
// Weights via wave-uniform scalar loads (s_load); LDS holds only x / pooled1.
// =======================================================================
__global__ __launch_bounds__(512) void k_convs(const float* __restrict__ x,
        const float* __restrict__ w1, const float* __restrict__ b1,
        const float* __restrict__ w2, const float* __restrict__ b2,
        float* __restrict__ nodes,
        const int* __restrict__ ei, int E, int es,
        int* __restrict__ rptr, float* __restrict__ dis, int* __restrict__ adj) {
    __shared__ float sx[CIN][268];     // x tile, g in [4r0-6, 4r0+262)
    __shared__ float s1[16][132];      // pooled conv1, p in [2r0-2, 2r0+130)
    __shared__ int lcnt[512];          // graph block only
    __shared__ int sp[512];
    __shared__ int lcur[512];
    int tid = threadIdx.x;

    if (blockIdx.x == 1024) {
        // ---- CSR build for the per-sample graph (replicated across batch) --
        int t = tid;
        lcnt[t] = 0;
        __syncthreads();
        for (int i = t; i < es; i += 512) atomicAdd(&lcnt[ei[E + i]], 1);
        __syncthreads();
        int c = lcnt[t];
        sp[t] = c;
        __syncthreads();
        for (int off = 1; off < 512; off <<= 1) {
            int v = sp[t];
            int add = (t >= off) ? sp[t - off] : 0;
            __syncthreads();
            sp[t] = v + add;
            __syncthreads();
        }
        int excl = sp[t] - c;
        rptr[t] = excl;
        if (t == 511) rptr[512] = es;
        dis[t] = rsqrtf((float)c + 1.0f);
        lcur[t] = excl;
        __syncthreads();
        for (int i = t; i < es; i += 512) {
            int row = ei[i], col = ei[E + i];
            int pos = atomicAdd(&lcur[col], 1);
            adj[pos] = row;
        }
        return;
    }

    int b  = blockIdx.x >> 3;
    int r0 = (blockIdx.x & 7) * 64;
    int wv   = __builtin_amdgcn_readfirstlane(tid >> 6);   // wave 0..7
    int lane = tid & 63;

    // stage x tile
    for (int idx = tid; idx < CIN * 268; idx += 512) {
        int c = idx / 268, j = idx - c * 268;
        int g = 4 * r0 - 6 + j;
        float v = 0.f;
        if (g >= 0 && g < TT) v = x[(b * CIN + c) * TT + g];
        sx[c][j] = v;
    }
    __syncthreads();

    // phase B: pooled conv1 -> s1.  wave wv does out-channels wv*2, wv*2+1
#pragma unroll
    for (int cc = 0; cc < 2; ++cc) {
        int c1 = wv * 2 + cc;
        float bias1 = b1[c1];
        for (int pp = lane; pp < 132; pp += 64) {
            int p = 2 * r0 - 2 + pp;
            float val = 0.f;
            if (p >= 0 && p < 1024) {
                float a0 = bias1, a1 = bias1;
#pragma unroll
                for (int c = 0; c < CIN; ++c) {
                    const float2* px = (const float2*)&sx[c][2 * pp];
                    float2 q0 = px[0], q1 = px[1], q2 = px[2];
                    const float* wp = &w1[(c1 * CIN + c) * 5];
                    float k0 = wp[0], k1 = wp[1], k2 = wp[2], k3 = wp[3], k4 = wp[4];
                    a0 += q0.x*k0 + q0.y*k1 + q1.x*k2 + q1.y*k3 + q2.x*k4;
                    a1 += q0.y*k0 + q1.x*k1 + q1.y*k2 + q2.x*k3 + q2.y*k4;
                }
                val = fmaxf(fmaxf(a0, a1), 0.f);
            }
            s1[c1][pp] = val;
        }
    }
    __syncthreads();

    // phase C: conv2 + relu + pool -> nodes. wave wv does out-channels wv*4..+3
    int rl = lane;                     // local node 0..63
    float acc0[4], acc1[4];
#pragma unroll
    for (int o = 0; o < 4; ++o) {
        float bv = b2[wv * 4 + o];
        acc0[o] = bv; acc1[o] = bv;
    }
#pragma unroll
    for (int c = 0; c < 16; ++c) {
        const float2* ps = (const float2*)&s1[c][2 * rl];
        float2 q0 = ps[0], q1 = ps[1], q2 = ps[2];
#pragma unroll
        for (int o = 0; o < 4; ++o) {
            const float* wp = &w2[((wv * 4 + o) * 16 + c) * 5];
            float k0 = wp[0], k1 = wp[1], k2 = wp[2], k3 = wp[3], k4 = wp[4];
            acc0[o] += q0.x*k0 + q0.y*k1 + q1.x*k2 + q1.y*k3 + q2.x*k4;
            acc1[o] += q0.y*k0 + q1.x*k1 + q1.y*k2 + q2.x*k3 + q2.y*k4;
        }
    }
    int n = b * RR + r0 + rl;
    float4 ov;
    ov.x = fmaxf(fmaxf(acc0[0], acc1[0]), 0.f);
    ov.y = fmaxf(fmaxf(acc0[1], acc1[1]), 0.f);
    ov.z = fmaxf(fmaxf(acc0[2], acc1[2]), 0.f);
    ov.w = fmaxf(fmaxf(acc0[3], acc1[3]), 0.f);
    *(float4*)&nodes[n * 32 + wv * 4] = ov;
}

// =======================================================================
// Fused layer-1: gather on 32-dim + lin1 + bias + relu -> h1 (bf16)
// =======================================================================
__global__ __launch_bounds__(256) void k_gl1(const int* __restrict__ rptr,
        const int* __restrict__ adj, const float* __restrict__ dis,
        const float* __restrict__ nodes, const float* __restrict__ w,
        const float* __restrict__ bias, unsigned short* __restrict__ h16) {
    __shared__ float srow[32][32];
    __shared__ float sw[32 * 128];
    int bid = (blockIdx.x & 7) * 256 + (blockIdx.x >> 3);   // XCD swizzle, 2048
    int tid = threadIdx.x;
    int nbase = bid * 32;
    int b = nbase >> 9;
    const float* hb = nodes + (size_t)b * RR * 32;

    {   // weights -> LDS
        const float4* src = (const float4*)w;
        float4* dst = (float4*)sw;
#pragma unroll
        for (int i = 0; i < 4; ++i) dst[tid + i * 256] = src[tid + i * 256];
    }

    int ln   = tid >> 3;
    int lane = tid & 7;
    int r = (nbase & 511) + ln;
    int s = rptr[r], e = rptr[r + 1];
    float dn = dis[r];
    float4 acc = make_float4(0.f, 0.f, 0.f, 0.f);
    for (int base = s; base < e; base += 8) {
        int j = base + lane;
        int src = 0; float nd = 0.f;
        if (j < e) { src = adj[j]; nd = dis[src]; }
        int cnt = min(8, e - base);
        int k = 0;
        for (; k + 4 <= cnt; k += 4) {
            int   s0 = __shfl(src, k, 8),     s1 = __shfl(src, k + 1, 8);
            int   s2 = __shfl(src, k + 2, 8), s3 = __shfl(src, k + 3, 8);
            float n0 = __shfl(nd, k, 8),      n1 = __shfl(nd, k + 1, 8);
            float n2 = __shfl(nd, k + 2, 8),  n3 = __shfl(nd, k + 3, 8);
            float4 v0 = *(const float4*)&hb[(size_t)s0 * 32 + lane * 4];
            float4 v1 = *(const float4*)&hb[(size_t)s1 * 32 + lane * 4];
            float4 v2 = *(const float4*)&hb[(size_t)s2 * 32 + lane * 4];
            float4 v3 = *(const float4*)&hb[(size_t)s3 * 32 + lane * 4];
            float w0 = dn * n0, w1 = dn * n1, w2 = dn * n2, w3 = dn * n3;
            acc.x += w0*v0.x + w1*v1.x + w2*v2.x + w3*v3.x;
            acc.y += w0*v0.y + w1*v1.y + w2*v2.y + w3*v3.y;
            acc.z += w0*v0.z + w1*v1.z + w2*v2.z + w3*v3.z;
            acc.w += w0*v0.w + w1*v1.w + w2*v2.w + w3*v3.w;
        }
        for (; k < cnt; ++k) {
            int   sk = __shfl(src, k, 8);
            float nk = __shfl(nd, k, 8);
            float4 v = *(const float4*)&hb[(size_t)sk * 32 + lane * 4];
            float wgt = dn * nk;
            acc.x += wgt * v.x; acc.y += wgt * v.y;
            acc.z += wgt * v.z; acc.w += wgt * v.w;
        }
    }
    {
        float4 v = *(const float4*)&hb[(size_t)r * 32 + lane * 4];
        float wgt = dn * dn;
        acc.x += wgt * v.x; acc.y += wgt * v.y;
        acc.z += wgt * v.z; acc.w += wgt * v.w;
    }
    *(float4*)&srow[ln][lane * 4] = acc;
    __syncthreads();

    int fq = tid & 31;
    int ng = tid >> 5;
    float a[4][4];
#pragma unroll
    for (int j = 0; j < 4; ++j)
#pragma unroll
        for (int q = 0; q < 4; ++q) a[j][q] = 0.f;
#pragma unroll
    for (int c = 0; c < 32; ++c) {
        float4 wvv = *(const float4*)&sw[c * 128 + fq * 4];
#pragma unroll
        for (int j = 0; j < 4; ++j) {
            float xc = srow[ng * 4 + j][c];
            a[j][0] += xc * wvv.x; a[j][1] += xc * wvv.y;
            a[j][2] += xc * wvv.z; a[j][3] += xc * wvv.w;
        }
    }
    float4 bv = *(const float4*)&bias[fq * 4];
#pragma unroll
    for (int j = 0; j < 4; ++j) {
        ushort4 o;
        o.x = f2bf(fmaxf(a[j][0] + bv.x, 0.f));
        o.y = f2bf(fmaxf(a[j][1] + bv.y, 0.f));
        o.z = f2bf(fmaxf(a[j][2] + bv.z, 0.f));
        o.w = f2bf(fmaxf(a[j][3] + bv.w, 0.f));
        *(ushort4*)&h16[(size_t)(nbase + ng * 4 + j) * 128 + fq * 4] = o;
    }
}

// =======================================================================
// lin2 via MFMA bf16: h2[N,128] = h1[N,128] @ W[128,128]   (bf16 in/out)
// =======================================================================
__global__ __launch_bounds__(256) void k_lin2(const unsigned short* __restrict__ g16,
        const float* __restrict__ w, unsigned short* __restrict__ h16) {
    __shared__ unsigned short srow[64][136];
    __shared__ unsigned short swT[128][136];
    int tid = threadIdx.x;
    int nbase = blockIdx.x * 64;

    {   // stage A rows (64x128 bf16)
        const ushort4* src = (const ushort4*)(g16 + (size_t)nbase * 128);
#pragma unroll
        for (int i = 0; i < 8; ++i) {
            int idx = tid + i * 256;
            int row = idx >> 5, col4 = idx & 31;
            ushort4 v = src[idx];
            *(ushort4*)&srow[row][col4 * 4] = v;
        }
    }
    {   // stage W^T as bf16
        for (int i = 0; i < 64; ++i) {
            int idx = i * 256 + tid;
            int c = idx >> 7, f = idx & 127;
            swT[f][c] = f2bf(w[idx]);
        }
    }
    __syncthreads();

    int wv  = tid >> 6;
    int lane = tid & 63;
    int m0 = wv * 16;
    int l15 = lane & 15;
    int quad = lane >> 4;
    f32x4 acc[8];
#pragma unroll
    for (int nt = 0; nt < 8; ++nt) acc[nt] = (f32x4){0.f, 0.f, 0.f, 0.f};
#pragma unroll
    for (int kc = 0; kc < 4; ++kc) {
        int k0 = kc * 32 + quad * 8;
        short8 a = *(const short8*)&srow[m0 + l15][k0];
#pragma unroll
        for (int nt = 0; nt < 8; ++nt) {
            short8 b = *(const short8*)&swT[nt * 16 + l15][k0];
            acc[nt] = __builtin_amdgcn_mfma_f32_16x16x32_bf16(a, b, acc[nt], 0, 0, 0);
        }
    }
#pragma unroll
    for (int nt = 0; nt < 8; ++nt) {
#pragma unroll
        for (int r = 0; r < 4; ++r) {
            int row = m0 + quad * 4 + r;
            int col = nt * 16 + l15;
            h16[(size_t)(nbase + row) * 128 + col] = f2bf(acc[nt][r]);
        }
    }
}

// ---- layer-2 gather (bf16 h) + self-loop + bias + relu + partial colsum ----
__global__ __launch_bounds__(256) void k_gather128(const int* __restrict__ rptr,
        const int* __restrict__ adj, const float* __restrict__ dis,
        const unsigned short* __restrict__ h, const float* __restrict__ bias,
        float* __restrict__ partial) {
    __shared__ float sred[8][128];
    int bid  = (blockIdx.x & 7) * 1024 + (blockIdx.x >> 3);  // XCD swizzle, 8192
    int tid  = threadIdx.x;
    int g    = tid >> 5;
    int lane = tid & 31;
    int node = bid * 8 + g;
    int b = node >> 9;
    int r = node & 511;
    const unsigned short* hb = h + (size_t)b * RR * 128;
    int s = rptr[r], e = rptr[r + 1];
    float dn = dis[r];
    float4 acc = make_float4(0.f, 0.f, 0.f, 0.f);
    for (int base = s; base < e; base += 32) {
        int j = base + lane;
        int src = 0; float nd = 0.f;
        if (j < e) { src = adj[j]; nd = dis[src]; }
        int cnt = min(32, e - base);
        int k = 0;
        for (; k + 4 <= cnt; k += 4) {
            int   s0 = __shfl(src, k, 32),     s1 = __shfl(src, k + 1, 32);
            int   s2 = __shfl(src, k + 2, 32), s3 = __shfl(src, k + 3, 32);
            float n0 = __shfl(nd, k, 32),      n1 = __shfl(nd, k + 1, 32);
            float n2 = __shfl(nd, k + 2, 32),  n3 = __shfl(nd, k + 3, 32);
            ushort4 u0 = *(const ushort4*)&hb[(size_t)s0 * 128 + lane * 4];
            ushort4 u1 = *(const ushort4*)&hb[(size_t)s1 * 128 + lane * 4];
            ushort4 u2 = *(const ushort4*)&hb[(size_t)s2 * 128 + lane * 4];
            ushort4 u3 = *(const ushort4*)&hb[(size_t)s3 * 128 + lane * 4];
            float w0 = dn * n0, w1 = dn * n1, w2 = dn * n2, w3 = dn * n3;
            acc.x += w0*bf2f(u0.x) + w1*bf2f(u1.x) + w2*bf2f(u2.x) + w3*bf2f(u3.x);
            acc.y += w0*bf2f(u0.y) + w1*bf2f(u1.y) + w2*bf2f(u2.y) + w3*bf2f(u3.y);
            acc.z += w0*bf2f(u0.z) + w1*bf2f(u1.z) + w2*bf2f(u2.z) + w3*bf2f(u3.z);
            acc.w += w0*bf2f(u0.w) + w1*bf2f(u1.w) + w2*bf2f(u2.w) + w3*bf2f(u3.w);
        }
        for (; k < cnt; ++k) {
            int   sk = __shfl(src, k, 32);
            float nk = __shfl(nd, k, 32);
            ushort4 u = *(const ushort4*)&hb[(size_t)sk * 128 + lane * 4];
            float wgt = dn * nk;
            acc.x += wgt * bf2f(u.x); acc.y += wgt * bf2f(u.y);
            acc.z += wgt * bf2f(u.z); acc.w += wgt * bf2f(u.w);
        }
    }
    ushort4 u = *(const ushort4*)&hb[(size_t)r * 128 + lane * 4];
    float wgt = dn * dn;
    float4 bv = *(const float4*)&bias[lane * 4];
    acc.x = fmaxf(acc.x + wgt * bf2f(u.x) + bv.x, 0.f);
    acc.y = fmaxf(acc.y + wgt * bf2f(u.y) + bv.y, 0.f);
    acc.z = fmaxf(acc.z + wgt * bf2f(u.z) + bv.z, 0.f);
    acc.w = fmaxf(acc.w + wgt * bf2f(u.w) + bv.w, 0.f);
    *(float4*)&sred[g][lane * 4] = acc;
    __syncthreads();
    if (tid < 128) {
        float ssum = 0.f;
#pragma unroll
        for (int j = 0; j < 8; ++j) ssum += sred[j][tid];
        partial[(size_t)bid * 128 + tid] = ssum;   // plain coalesced store
    }
}

// ---------------- fc: sum partials -> mean -> out[b] = mean @ fw + fb -------
__global__ __launch_bounds__(128) void k_fc(const float* __restrict__ partial,
        const float* __restrict__ fw, const float* __restrict__ fb,
        float* __restrict__ out) {
    __shared__ float sm[HID];
    int b = blockIdx.x, f = threadIdx.x;
    float acc = 0.f;
#pragma unroll 8
    for (int j = 0; j < 64; ++j) acc += partial[(size_t)(b * 64 + j) * 128 + f];
    sm[f] = acc * (1.0f / RR);
    __syncthreads();
    if (f < NOUT) {
        float s = fb[f];
#pragma unroll
        for (int c = 0; c < HID; ++c) s += sm[c] * fw[c * NOUT + f];
        out[b * NOUT + f] = s;
    }
}

extern "C" void kernel_launch(void* const* d_in, const int* in_sizes, int n_in,
                              void* d_out, int out_size, void* d_ws, size_t ws_size,
                              hipStream_t stream) {
    const float* x   = (const float*)d_in[0];
    const int*   ei  = (const int*)d_in[1];
    const float* c1w = (const float*)d_in[2];
    const float* c1b = (const float*)d_in[3];
    const float* c2w = (const float*)d_in[4];
    const float* c2b = (const float*)d_in[5];
    const float* g1w = (const float*)d_in[6];
    const float* g1b = (const float*)d_in[7];
    const float* g2w = (const float*)d_in[8];
    const float* g2b = (const float*)d_in[9];
    const float* fw  = (const float*)d_in[10];
    const float* fb  = (const float*)d_in[11];
    float* out = (float*)d_out;
    int E  = in_sizes[1] / 2;   // total edges (1048576)
    int es = E / BB;            // edges per sample graph (8192)

    char* ws = (char*)d_ws;
    float*          nodes   = (float*)(ws);                        // 8 MB  [N,32] f32
    unsigned short* bufA16  = (unsigned short*)(ws + (8u  << 20)); // 16 MB [N,128] bf16
    unsigned short* bufC16  = (unsigned short*)(ws + (24u << 20)); // 16 MB [N,128] bf16
    int*   rptr    = (int*)  (ws + (40u << 20));                   // [513]
    float* dis     = (float*)(ws + (40u << 20) + 4096);            // [512]
    int*   adj     = (int*)  (ws + (40u << 20) + 8192);            // 32 KB [es]
    float* partial = (float*)(ws + (41u << 20));                   // 4 MB [8192,128]

    // fused temporal convs (blocks 0..1023) + CSR graph build (block 1024)
    k_convs<<<BB * 8 + 1, 512, 0, stream>>>(x, c1w, c1b, c2w, c2b, nodes,
                                            ei, E, es, rptr, dis, adj);

    // GCN layer 1: fused gather(32-dim) + linear + bias + relu -> bf16
    k_gl1<<<NN / 32, 256, 0, stream>>>(rptr, adj, dis, nodes, g1w, g1b, bufA16);

    // GCN layer 2: MFMA linear (bf16), then gather (+bias+relu) -> partials
    k_lin2<<<NN / 64, 256, 0, stream>>>(bufA16, g2w, bufC16);
    k_gather128<<<NN / 8, 256, 0, stream>>>(rptr, adj, dis, bufC16, g2b, partial);

    // mean (from partials) + fc
    k_fc<<<BB, 128, 0, stream>>>(partial, fw, fb, out);
}